// Round 1
// baseline (92776.044 us; speedup 1.0000x reference)
//
#include <hip/hip_runtime.h>
#include <hip/hip_bf16.h>
#include <stdint.h>
#include <stddef.h>

// ---------------------------------------------------------------------------
// LFADS forward on MI355X (round 0: f32 compute, correctness-first).
//  - 4 independent encoder GRU chains (egf, ecf fwd; egb, ecb bwd), each
//    split (32 j-groups x 2 b-halves) over 64 persistent WGs; one
//    device-scope barrier per step; hidden state ping-pongs through L2.
//  - Generator: factor input folded into composite M = W_f @ fac_w so each
//    step needs only 2 barriers (after c, after g). 128 main WGs
//    (64 j-groups x 2 b-halves) + 32 output-MLP WGs running one step behind.
//  - Weights read from global with readfirstlane-uniform bases (s_load path).
//  - Encoder state archives stored bf16 (workspace size insurance).
// ---------------------------------------------------------------------------

#define B_    128
#define T_    1000
#define DIN_  64
#define E_    256
#define F_    64
#define H1_   80
#define DOUT_ 64
#define GEB   (E_*B_)
#define CLIPV 5.0f
#define LVMIN_ (-9.210340371976182f)

__device__ __forceinline__ float sigm_(float x) { return 1.0f/(1.0f + expf(-x)); }

// Device-scope barrier among co-resident workgroups (monotonic counter).
__device__ __forceinline__ void gbar(unsigned* ctr, unsigned target) {
  __syncthreads();   // all WG stores drained (vmcnt) before arrival
  if (threadIdx.x == 0) {
    __hip_atomic_fetch_add(ctr, 1u, __ATOMIC_RELEASE, __HIP_MEMORY_SCOPE_AGENT);
    int guard = 0;
    while (__hip_atomic_load(ctr, __ATOMIC_RELAXED, __HIP_MEMORY_SCOPE_AGENT) < target) {
      __builtin_amdgcn_s_sleep(2);
      if (++guard > 4000000) break;   // failsafe: never hang the bench
    }
  }
  __syncthreads();
  __builtin_amdgcn_fence(__ATOMIC_ACQUIRE, "agent");
}

// ------------------------- prep kernels ------------------------------------

// x[B][T][DIN] -> xT[T][DIN][B] (f32), tiled through LDS.
__global__ void k_transpose_x(const float* __restrict__ x, float* __restrict__ xT) {
  __shared__ float tile[64][65];
  const int t = blockIdx.x, bh = blockIdx.y;
  const int lane = threadIdx.x & 63, w = threadIdx.x >> 6;
  for (int i = 0; i < 16; ++i) {
    const int bl = w*16 + i;
    tile[bl][lane] = x[(size_t)(bh*64 + bl)*(T_*DIN_) + (size_t)t*DIN_ + lane];
  }
  __syncthreads();
  for (int i = 0; i < 16; ++i) {
    const int k = w*16 + i;
    xT[(size_t)t*(DIN_*B_) + (size_t)k*B_ + bh*64 + lane] = tile[lane][k];
  }
}

// eps_u[B][T][2] -> epsT[T][2][B]
__global__ void k_transpose_eps(const float* __restrict__ eps_u, float* __restrict__ epsT) {
  const int t = blockIdx.x;
  const int o = threadIdx.x >> 7, b = threadIdx.x & 127;
  epsT[(size_t)t*2*B_ + o*B_ + b] = eps_u[(size_t)b*(T_*2) + t*2 + o];
}

// fac_w[F][E] -> facT[E][F]
__global__ void k_transpose_fac(const float* __restrict__ facw, float* __restrict__ facT) {
  const int idx = blockIdx.x*256 + threadIdx.x;   // 256*64
  const int k = idx >> 6, fd = idx & 63;
  facT[idx] = facw[(size_t)fd*E_ + k];
}

// M[768][E] = con_wih[:,512:576] @ fac_w ; Wfb[768] = con_wih[:,512:576] @ fac_b
__global__ void k_composite(const float* __restrict__ conwih, const float* __restrict__ facw,
                            const float* __restrict__ facb, float* __restrict__ M,
                            float* __restrict__ Wfb) {
  const int idx = blockIdx.x*256 + threadIdx.x;   // 768*256
  const int j = idx >> 8, k = idx & 255;
  float acc = 0.0f;
  for (int ff = 0; ff < F_; ++ff)
    acc += conwih[(size_t)j*576 + 512 + ff] * facw[(size_t)ff*E_ + k];
  M[(size_t)j*E_ + k] = acc;
  if (k == 0) {
    float a = 0.0f;
    for (int ff = 0; ff < F_; ++ff) a += conwih[(size_t)j*576 + 512 + ff] * facb[ff];
    Wfb[j] = a;
  }
}

// ------------------------- encoder -----------------------------------------

struct EncArgs {
  const float* xT;             // [T][DIN][B]
  const float* wih[4];
  const float* whh[4];
  const float* bih[4];
  const float* bhh[4];
  float* hT;                   // [4][2][E][B]
  __hip_bfloat16* efS;         // [T][E][B]
  __hip_bfloat16* ebS;
  unsigned* ctr;               // chain c at ctr[c*32]
};

__global__ __launch_bounds__(256, 1) void k_encoder(EncArgs a) {
  const int chain = blockIdx.x >> 6;
  const int rnk   = blockIdx.x & 63;
  const int jjg   = rnk >> 1;            // 32 groups of 8 j
  const int bg    = rnk & 1;             // b half
  const int lane  = threadIdx.x & 63;
  const int w     = threadIdx.x >> 6;
  const int b     = bg*64 + lane;

  const float* wih = a.wih[chain];
  const float* whh = a.whh[chain];
  const float* bih = a.bih[chain];
  const float* bhh = a.bhh[chain];
  float* hTc = a.hT + (size_t)chain*2*GEB;
  unsigned* ctr = a.ctr + chain*32;
  const bool bwd = (chain >= 2);
  __hip_bfloat16* st = (chain == 1) ? a.efS : (chain == 3 ? a.ebS : nullptr);

  int j0 = jjg*8 + 2*w;
  j0 = __builtin_amdgcn_readfirstlane(j0);
  const int j1 = j0 + 1;

  const float brz0 = bih[j0] + bhh[j0];
  const float brz1 = bih[j1] + bhh[j1];
  const float bz0  = bih[E_+j0] + bhh[E_+j0];
  const float bz1  = bih[E_+j1] + bhh[E_+j1];
  const float bni0 = bih[2*E_+j0], bni1 = bih[2*E_+j1];
  const float bnh0 = bhh[2*E_+j0], bnh1 = bhh[2*E_+j1];

  const float4* wr0x = (const float4*)(wih + (size_t)j0*DIN_);
  const float4* wz0x = (const float4*)(wih + (size_t)(E_+j0)*DIN_);
  const float4* wn0x = (const float4*)(wih + (size_t)(2*E_+j0)*DIN_);
  const float4* wr1x = (const float4*)(wih + (size_t)j1*DIN_);
  const float4* wz1x = (const float4*)(wih + (size_t)(E_+j1)*DIN_);
  const float4* wn1x = (const float4*)(wih + (size_t)(2*E_+j1)*DIN_);
  const float4* wr0h = (const float4*)(whh + (size_t)j0*E_);
  const float4* wz0h = (const float4*)(whh + (size_t)(E_+j0)*E_);
  const float4* wn0h = (const float4*)(whh + (size_t)(2*E_+j0)*E_);
  const float4* wr1h = (const float4*)(whh + (size_t)j1*E_);
  const float4* wz1h = (const float4*)(whh + (size_t)(E_+j1)*E_);
  const float4* wn1h = (const float4*)(whh + (size_t)(2*E_+j1)*E_);

  int p = 0;
  for (int t = 0; t < T_; ++t) {
    const int tt = bwd ? (T_-1-t) : t;
    const float* xp = a.xT + (size_t)tt*DIN_*B_ + b;
    const float* hp = hTc + (size_t)p*GEB + b;
    float ar0=0,az0=0,an0=0,ah0=0, ar1=0,az1=0,an1=0,ah1=0;
    for (int k4 = 0; k4 < DIN_/4; ++k4) {
      const float x0 = xp[(4*k4+0)*B_], x1 = xp[(4*k4+1)*B_];
      const float x2 = xp[(4*k4+2)*B_], x3 = xp[(4*k4+3)*B_];
      float4 v;
      v = wr0x[k4]; ar0 += v.x*x0 + v.y*x1 + v.z*x2 + v.w*x3;
      v = wz0x[k4]; az0 += v.x*x0 + v.y*x1 + v.z*x2 + v.w*x3;
      v = wn0x[k4]; an0 += v.x*x0 + v.y*x1 + v.z*x2 + v.w*x3;
      v = wr1x[k4]; ar1 += v.x*x0 + v.y*x1 + v.z*x2 + v.w*x3;
      v = wz1x[k4]; az1 += v.x*x0 + v.y*x1 + v.z*x2 + v.w*x3;
      v = wn1x[k4]; an1 += v.x*x0 + v.y*x1 + v.z*x2 + v.w*x3;
    }
    for (int k4 = 0; k4 < E_/4; ++k4) {
      const float h0 = hp[(4*k4+0)*B_], h1 = hp[(4*k4+1)*B_];
      const float h2 = hp[(4*k4+2)*B_], h3 = hp[(4*k4+3)*B_];
      float4 v;
      v = wr0h[k4]; ar0 += v.x*h0 + v.y*h1 + v.z*h2 + v.w*h3;
      v = wz0h[k4]; az0 += v.x*h0 + v.y*h1 + v.z*h2 + v.w*h3;
      v = wn0h[k4]; ah0 += v.x*h0 + v.y*h1 + v.z*h2 + v.w*h3;
      v = wr1h[k4]; ar1 += v.x*h0 + v.y*h1 + v.z*h2 + v.w*h3;
      v = wz1h[k4]; az1 += v.x*h0 + v.y*h1 + v.z*h2 + v.w*h3;
      v = wn1h[k4]; ah1 += v.x*h0 + v.y*h1 + v.z*h2 + v.w*h3;
    }
    const float hprev0 = hp[j0*B_];
    const float hprev1 = hp[j1*B_];
    const float r0 = sigm_(ar0 + brz0);
    const float z0 = sigm_(az0 + bz0);
    const float n0 = tanhf(an0 + bni0 + r0*(ah0 + bnh0));
    const float h0n = fminf((1.0f - z0)*n0 + z0*hprev0, CLIPV);
    const float r1 = sigm_(ar1 + brz1);
    const float z1 = sigm_(az1 + bz1);
    const float n1 = tanhf(an1 + bni1 + r1*(ah1 + bnh1));
    const float h1n = fminf((1.0f - z1)*n1 + z1*hprev1, CLIPV);
    float* hq = hTc + (size_t)(p^1)*GEB;
    hq[j0*B_ + b] = h0n;
    hq[j1*B_ + b] = h1n;
    if (st) {
      st[(size_t)tt*GEB + j0*B_ + b] = __float2bfloat16(h0n);
      st[(size_t)tt*GEB + j1*B_ + b] = __float2bfloat16(h1n);
    }
    gbar(ctr, (unsigned)(t+1)*64u);
    p ^= 1;
  }
}

// ------------------------- g0 sample ----------------------------------------

__global__ void k_g0(const float* __restrict__ hT, const float* __restrict__ g0mw,
                     const float* __restrict__ g0mb, const float* __restrict__ g0vw,
                     const float* __restrict__ g0vb, const float* __restrict__ eps_g0,
                     float* __restrict__ gT) {
  const int b = threadIdx.x & 127;
  const int half = threadIdx.x >> 7;
  const int kout = blockIdx.x*2 + half;
  const float* hf = hT;                 // chain0 (egf), buffer 0 (t=999 wrote buf 0)
  const float* hb = hT + 4*GEB;         // chain2 (egb), buffer 0
  const float* mrow = g0mw + (size_t)kout*512;
  const float* vrow = g0vw + (size_t)kout*512;
  float dm = 0.0f, dv = 0.0f;
  for (int k = 0; k < E_; ++k) {
    const float hv = hf[k*B_ + b];
    dm += mrow[k]*hv; dv += vrow[k]*hv;
  }
  for (int k = 0; k < E_; ++k) {
    const float hv = hb[k*B_ + b];
    dm += mrow[256+k]*hv; dv += vrow[256+k]*hv;
  }
  const float lv = fmaxf(dv + g0vb[kout], LVMIN_);
  const float g = eps_g0[(size_t)b*E_ + kout]*expf(0.5f*lv) + dm + g0mb[kout];
  gT[kout*B_ + b] = g;
}

// ------------------------- generator ----------------------------------------

struct GenArgs {
  const __hip_bfloat16* efS; const __hip_bfloat16* ebS;
  const float* epsT;         // [T][2][B]
  const float* conwih; const float* conwhh; const float* conbih; const float* conbhh;
  const float* M; const float* Wfb;
  const float* genwih; const float* genwhh; const float* genbih; const float* genbhh;
  const float* umw; const float* umb; const float* uvw; const float* uvb;
  const float* facT; const float* facb;
  const float* f1w; const float* f1b;
  const float* clw; const float* clb;
  float* gT; float* cT;      // [2][E][B]
  float* out;                // [B][T][DOUT]
  unsigned* ctr;             // A at [0], C at [32]
};

__global__ __launch_bounds__(256, 1) void k_generator(GenArgs a) {
  __shared__ float s_u[4][64];
  __shared__ float s_f1T[64*H1_];
  __shared__ float s_clT[H1_*64];
  __shared__ float s_f[4][64];
  __shared__ float s_h1[4][H1_];
  unsigned* ctrA = a.ctr;
  unsigned* ctrC = a.ctr + 32;
  const int lane = threadIdx.x & 63;
  const int w = threadIdx.x >> 6;

  if (blockIdx.x < 128) {
    // ---------------- main WG: controller + u + generator ----------------
    const int jjgq = blockIdx.x >> 1;
    const int bg = blockIdx.x & 1;
    const int b = bg*64 + lane;
    int j = jjgq*4 + w;
    j = __builtin_amdgcn_readfirstlane(j);

    const float4* cwr_e = (const float4*)(a.conwih + (size_t)j*576);
    const float4* cwz_e = (const float4*)(a.conwih + (size_t)(E_+j)*576);
    const float4* cwn_e = (const float4*)(a.conwih + (size_t)(2*E_+j)*576);
    const float4* cMr = (const float4*)(a.M + (size_t)j*E_);
    const float4* cMz = (const float4*)(a.M + (size_t)(E_+j)*E_);
    const float4* cMn = (const float4*)(a.M + (size_t)(2*E_+j)*E_);
    const float4* cwr_h = (const float4*)(a.conwhh + (size_t)j*E_);
    const float4* cwz_h = (const float4*)(a.conwhh + (size_t)(E_+j)*E_);
    const float4* cwn_h = (const float4*)(a.conwhh + (size_t)(2*E_+j)*E_);
    const float brz_c = a.conbih[j] + a.conbhh[j] + a.Wfb[j];
    const float bz_c  = a.conbih[E_+j] + a.conbhh[E_+j] + a.Wfb[E_+j];
    const float bni_c = a.conbih[2*E_+j] + a.Wfb[2*E_+j];
    const float bnh_c = a.conbhh[2*E_+j];

    const float4* gwr_h = (const float4*)(a.genwhh + (size_t)j*E_);
    const float4* gwz_h = (const float4*)(a.genwhh + (size_t)(E_+j)*E_);
    const float4* gwn_h = (const float4*)(a.genwhh + (size_t)(2*E_+j)*E_);
    const float gur0 = a.genwih[j*2],        gur1 = a.genwih[j*2+1];
    const float guz0 = a.genwih[(E_+j)*2],   guz1 = a.genwih[(E_+j)*2+1];
    const float gun0 = a.genwih[(2*E_+j)*2], gun1 = a.genwih[(2*E_+j)*2+1];
    const float brz_g = a.genbih[j] + a.genbhh[j];
    const float bz_g  = a.genbih[E_+j] + a.genbhh[E_+j];
    const float bni_g = a.genbih[2*E_+j];
    const float bnh_g = a.genbhh[2*E_+j];

    const float4* uw = (const float4*)((w < 2) ? (a.umw + (size_t)w*E_)
                                               : (a.uvw + (size_t)(w-2)*E_));
    const float ub = (w < 2) ? a.umb[w] : a.uvb[w-2];

    int p = 0;
    for (int t = 0; t < T_; ++t) {
      const __hip_bfloat16* efp = a.efS + (size_t)t*GEB + b;
      const __hip_bfloat16* ebp = a.ebS + (size_t)t*GEB + b;
      const float* gp = a.gT + (size_t)p*GEB + b;
      const float* cp = a.cT + (size_t)p*GEB + b;
      float ar=0, az=0, an=0, ah=0;
      for (int k4 = 0; k4 < 64; ++k4) {       // ef part
        const float e0 = __bfloat162float(efp[(4*k4+0)*B_]);
        const float e1 = __bfloat162float(efp[(4*k4+1)*B_]);
        const float e2 = __bfloat162float(efp[(4*k4+2)*B_]);
        const float e3 = __bfloat162float(efp[(4*k4+3)*B_]);
        float4 v;
        v = cwr_e[k4]; ar += v.x*e0 + v.y*e1 + v.z*e2 + v.w*e3;
        v = cwz_e[k4]; az += v.x*e0 + v.y*e1 + v.z*e2 + v.w*e3;
        v = cwn_e[k4]; an += v.x*e0 + v.y*e1 + v.z*e2 + v.w*e3;
      }
      for (int k4 = 0; k4 < 64; ++k4) {       // eb part (wih cols 256:512)
        const float e0 = __bfloat162float(ebp[(4*k4+0)*B_]);
        const float e1 = __bfloat162float(ebp[(4*k4+1)*B_]);
        const float e2 = __bfloat162float(ebp[(4*k4+2)*B_]);
        const float e3 = __bfloat162float(ebp[(4*k4+3)*B_]);
        float4 v;
        v = cwr_e[64+k4]; ar += v.x*e0 + v.y*e1 + v.z*e2 + v.w*e3;
        v = cwz_e[64+k4]; az += v.x*e0 + v.y*e1 + v.z*e2 + v.w*e3;
        v = cwn_e[64+k4]; an += v.x*e0 + v.y*e1 + v.z*e2 + v.w*e3;
      }
      for (int k4 = 0; k4 < 64; ++k4) {       // g part (composite M)
        const float g0 = gp[(4*k4+0)*B_], g1 = gp[(4*k4+1)*B_];
        const float g2 = gp[(4*k4+2)*B_], g3 = gp[(4*k4+3)*B_];
        float4 v;
        v = cMr[k4]; ar += v.x*g0 + v.y*g1 + v.z*g2 + v.w*g3;
        v = cMz[k4]; az += v.x*g0 + v.y*g1 + v.z*g2 + v.w*g3;
        v = cMn[k4]; an += v.x*g0 + v.y*g1 + v.z*g2 + v.w*g3;
      }
      for (int k4 = 0; k4 < 64; ++k4) {       // c part (recurrent)
        const float c0 = cp[(4*k4+0)*B_], c1 = cp[(4*k4+1)*B_];
        const float c2 = cp[(4*k4+2)*B_], c3 = cp[(4*k4+3)*B_];
        float4 v;
        v = cwr_h[k4]; ar += v.x*c0 + v.y*c1 + v.z*c2 + v.w*c3;
        v = cwz_h[k4]; az += v.x*c0 + v.y*c1 + v.z*c2 + v.w*c3;
        v = cwn_h[k4]; ah += v.x*c0 + v.y*c1 + v.z*c2 + v.w*c3;
      }
      const float cprev = cp[j*B_];
      const float r = sigm_(ar + brz_c);
      const float z = sigm_(az + bz_c);
      const float n = tanhf(an + bni_c + r*(ah + bnh_c));
      const float cn = fminf((1.0f - z)*n + z*cprev, CLIPV);
      a.cT[(size_t)(p^1)*GEB + j*B_ + b] = cn;
      gbar(ctrA, (unsigned)(t+1)*160u);

      // ---- u sample (per-wave dot over fresh c) ----
      {
        const float* cq = a.cT + (size_t)(p^1)*GEB + b;
        float du = 0.0f;
        for (int k4 = 0; k4 < 64; ++k4) {
          const float c0 = cq[(4*k4+0)*B_], c1 = cq[(4*k4+1)*B_];
          const float c2 = cq[(4*k4+2)*B_], c3 = cq[(4*k4+3)*B_];
          const float4 v = uw[k4];
          du += v.x*c0 + v.y*c1 + v.z*c2 + v.w*c3;
        }
        s_u[w][lane] = du + ub;
        __syncthreads();
        if (w < 2) {
          const float lv = fmaxf(s_u[2+w][lane], LVMIN_);
          const float uu = a.epsT[(size_t)t*2*B_ + w*B_ + b]*expf(0.5f*lv) + s_u[w][lane];
          s_u[w][lane] = uu;
        }
        __syncthreads();
      }
      const float u0 = s_u[0][lane], u1 = s_u[1][lane];

      // ---- generator GRU ----
      float gr=0, gz=0, gh=0;
      for (int k4 = 0; k4 < 64; ++k4) {
        const float g0 = gp[(4*k4+0)*B_], g1 = gp[(4*k4+1)*B_];
        const float g2 = gp[(4*k4+2)*B_], g3 = gp[(4*k4+3)*B_];
        float4 v;
        v = gwr_h[k4]; gr += v.x*g0 + v.y*g1 + v.z*g2 + v.w*g3;
        v = gwz_h[k4]; gz += v.x*g0 + v.y*g1 + v.z*g2 + v.w*g3;
        v = gwn_h[k4]; gh += v.x*g0 + v.y*g1 + v.z*g2 + v.w*g3;
      }
      const float gprev = gp[j*B_];
      const float rg = sigm_(gr + gur0*u0 + gur1*u1 + brz_g);
      const float zg = sigm_(gz + guz0*u0 + guz1*u1 + bz_g);
      const float ng = tanhf(gun0*u0 + gun1*u1 + bni_g + rg*(gh + bnh_g));
      const float gn = fminf((1.0f - zg)*ng + zg*gprev, CLIPV);
      a.gT[(size_t)(p^1)*GEB + j*B_ + b] = gn;
      gbar(ctrC, (unsigned)(t+1)*160u);
      p ^= 1;
    }
  } else {
    // ---------------- output-MLP WG: fac -> relu(f1) -> cl, one step behind
    const int oid = blockIdx.x - 128;
    const int bu = __builtin_amdgcn_readfirstlane(oid*4 + w);
    for (int idx = threadIdx.x; idx < 64*H1_; idx += 256) {   // f1T[kf][hd]
      const int kf = idx / H1_, hd = idx % H1_;
      s_f1T[idx] = a.f1w[(size_t)hd*64 + kf];
    }
    for (int idx = threadIdx.x; idx < H1_*64; idx += 256) {   // clT[kh][od]
      const int kh = idx >> 6, od = idx & 63;
      s_clT[idx] = a.clw[(size_t)od*H1_ + kh];
    }
    __syncthreads();
    const float facb_l = a.facb[lane];
    const float clb_l  = a.clb[lane];
    const float f1b_a  = a.f1b[lane];
    const float f1b_b  = (lane < H1_ - 64) ? a.f1b[64 + lane] : 0.0f;
    for (int t = 0; t <= T_; ++t) {
      if (t > 0) {
        const int tt = t - 1;
        const float* gq = a.gT + (size_t)((tt + 1) & 1)*GEB;
        float f = facb_l;
        for (int k = 0; k < E_; ++k)
          f += a.facT[k*64 + lane] * gq[k*B_ + bu];
        s_f[w][lane] = f;
        __syncthreads();
        float h1a = f1b_a, h1b = f1b_b;
        for (int kf = 0; kf < F_; ++kf) {
          const float fv = s_f[w][kf];
          h1a += s_f1T[kf*H1_ + lane]*fv;
          if (lane < H1_ - 64) h1b += s_f1T[kf*H1_ + 64 + lane]*fv;
        }
        s_h1[w][lane] = fmaxf(h1a, 0.0f);
        if (lane < H1_ - 64) s_h1[w][64 + lane] = fmaxf(h1b, 0.0f);
        __syncthreads();
        float o = clb_l;
        for (int kh = 0; kh < H1_; ++kh)
          o += s_clT[kh*64 + lane] * s_h1[w][kh];
        a.out[((size_t)bu*T_ + tt)*DOUT_ + lane] = o;
      }
      if (t == T_) break;
      gbar(ctrA, (unsigned)(t+1)*160u);
      gbar(ctrC, (unsigned)(t+1)*160u);
    }
  }
}

// ------------------------- host launcher ------------------------------------

extern "C" void kernel_launch(void* const* d_in, const int* in_sizes, int n_in,
                              void* d_out, int out_size, void* d_ws, size_t ws_size,
                              hipStream_t stream) {
  const float* x      = (const float*)d_in[0];
  const float* eps_g0 = (const float*)d_in[1];
  const float* eps_u  = (const float*)d_in[2];
  const float* egf_wih = (const float*)d_in[3],  *egf_whh = (const float*)d_in[4];
  const float* egf_bih = (const float*)d_in[5],  *egf_bhh = (const float*)d_in[6];
  const float* egb_wih = (const float*)d_in[7],  *egb_whh = (const float*)d_in[8];
  const float* egb_bih = (const float*)d_in[9],  *egb_bhh = (const float*)d_in[10];
  const float* ecf_wih = (const float*)d_in[11], *ecf_whh = (const float*)d_in[12];
  const float* ecf_bih = (const float*)d_in[13], *ecf_bhh = (const float*)d_in[14];
  const float* ecb_wih = (const float*)d_in[15], *ecb_whh = (const float*)d_in[16];
  const float* ecb_bih = (const float*)d_in[17], *ecb_bhh = (const float*)d_in[18];
  const float* con_wih = (const float*)d_in[19], *con_whh = (const float*)d_in[20];
  const float* con_bih = (const float*)d_in[21], *con_bhh = (const float*)d_in[22];
  const float* gen_wih = (const float*)d_in[23], *gen_whh = (const float*)d_in[24];
  const float* gen_bih = (const float*)d_in[25], *gen_bhh = (const float*)d_in[26];
  const float* g0m_w = (const float*)d_in[27], *g0m_b = (const float*)d_in[28];
  const float* g0v_w = (const float*)d_in[29], *g0v_b = (const float*)d_in[30];
  const float* um_w = (const float*)d_in[31], *um_b = (const float*)d_in[32];
  const float* uv_w = (const float*)d_in[33], *uv_b = (const float*)d_in[34];
  const float* fac_w = (const float*)d_in[35], *fac_b = (const float*)d_in[36];
  const float* f1_w = (const float*)d_in[37], *f1_b = (const float*)d_in[38];
  const float* cl_w = (const float*)d_in[39], *cl_b = (const float*)d_in[40];
  float* out = (float*)d_out;

  char* ws = (char*)d_ws;
  const size_t o_xT   = 0;                                   // f32 [T][DIN][B]
  const size_t o_epsT = o_xT   + 4ul*T_*DIN_*B_;             // f32 [T][2][B]
  const size_t o_facT = o_epsT + 4ul*T_*2*B_;                // f32 [E][F]
  const size_t o_M    = o_facT + 4ul*E_*F_;                  // f32 [768][E]
  const size_t o_Wfb  = o_M    + 4ul*768*E_;                 // f32 [768]
  const size_t o_efS  = o_Wfb  + 4096ul;                     // bf16 [T][E][B]
  const size_t o_ebS  = o_efS  + 2ul*T_*E_*B_;
  const size_t o_hT   = o_ebS  + 2ul*T_*E_*B_;               // f32 [4][2][E][B]
  const size_t o_gT   = o_hT   + 4ul*4*2*GEB;                // f32 [2][E][B]
  const size_t o_cT   = o_gT   + 4ul*2*GEB;
  const size_t o_ctr  = o_cT   + 4ul*2*GEB;                  // counters
  const size_t small_sz = (o_ctr + 4096ul) - o_hT;
  (void)ws_size; (void)in_sizes; (void)n_in; (void)out_size;

  float* xT = (float*)(ws + o_xT);
  float* epsT = (float*)(ws + o_epsT);
  float* facT = (float*)(ws + o_facT);
  float* M = (float*)(ws + o_M);
  float* Wfb = (float*)(ws + o_Wfb);
  __hip_bfloat16* efS = (__hip_bfloat16*)(ws + o_efS);
  __hip_bfloat16* ebS = (__hip_bfloat16*)(ws + o_ebS);
  float* hT = (float*)(ws + o_hT);
  float* gT = (float*)(ws + o_gT);
  float* cT = (float*)(ws + o_cT);
  unsigned* ctr = (unsigned*)(ws + o_ctr);

  // zero h/g/c ping-pong buffers and barrier counters (ws is poisoned 0xAA)
  hipMemsetAsync(ws + o_hT, 0, small_sz, stream);

  k_transpose_x<<<dim3(T_, 2), 256, 0, stream>>>(x, xT);
  k_transpose_eps<<<T_, 256, 0, stream>>>(eps_u, epsT);
  k_transpose_fac<<<64, 256, 0, stream>>>(fac_w, facT);
  k_composite<<<768, 256, 0, stream>>>(con_wih, fac_w, fac_b, M, Wfb);

  EncArgs ea;
  ea.xT = xT;
  ea.wih[0] = egf_wih; ea.whh[0] = egf_whh; ea.bih[0] = egf_bih; ea.bhh[0] = egf_bhh;
  ea.wih[1] = ecf_wih; ea.whh[1] = ecf_whh; ea.bih[1] = ecf_bih; ea.bhh[1] = ecf_bhh;
  ea.wih[2] = egb_wih; ea.whh[2] = egb_whh; ea.bih[2] = egb_bih; ea.bhh[2] = egb_bhh;
  ea.wih[3] = ecb_wih; ea.whh[3] = ecb_whh; ea.bih[3] = ecb_bih; ea.bhh[3] = ecb_bhh;
  ea.hT = hT; ea.efS = efS; ea.ebS = ebS; ea.ctr = ctr + 64;   // chain ctrs
  k_encoder<<<256, 256, 0, stream>>>(ea);

  k_g0<<<128, 256, 0, stream>>>(hT, g0m_w, g0m_b, g0v_w, g0v_b, eps_g0, gT);

  GenArgs ga;
  ga.efS = efS; ga.ebS = ebS; ga.epsT = epsT;
  ga.conwih = con_wih; ga.conwhh = con_whh; ga.conbih = con_bih; ga.conbhh = con_bhh;
  ga.M = M; ga.Wfb = Wfb;
  ga.genwih = gen_wih; ga.genwhh = gen_whh; ga.genbih = gen_bih; ga.genbhh = gen_bhh;
  ga.umw = um_w; ga.umb = um_b; ga.uvw = uv_w; ga.uvb = uv_b;
  ga.facT = facT; ga.facb = fac_b;
  ga.f1w = f1_w; ga.f1b = f1_b; ga.clw = cl_w; ga.clb = cl_b;
  ga.gT = gT; ga.cT = cT; ga.out = out; ga.ctr = ctr;          // A at 0, C at 32
  k_generator<<<160, 256, 0, stream>>>(ga);
}

// Round 3
// 76456.348 us; speedup vs baseline: 1.2135x; 1.2135x over previous
//
#include <hip/hip_runtime.h>
#include <hip/hip_bf16.h>
#include <stdint.h>
#include <stddef.h>

// ---------------------------------------------------------------------------
// LFADS forward on MI355X — round 2.
// Fits the PROVEN workspace (167,297,024 B from round 0; round 1 overflowed
// at ~397 MB and crashed). Structure:
//  - k_encoder: 4 chains x 64 WGs, LDS weights, [b][k] float4 state, slot
//    barrier per step. Archives ecf/ecb states bf16 [t][k][b].
//  - k_generator (256 WGs, all roles in one launch):
//      blocks   0..127: consumer (controller+u+generator GRUs, LDS weights)
//      blocks 128..223: producers — ge[t] = conwih[:, :512] @ [ef;eb]_t into a
//                       128-slot ring (aliased over dead xT), flag-synced
//      blocks 224..255: output MLP (fac->relu(f1)->cl), one step behind,
//                       weights in LDS (bf16), writes d_out directly.
//  - Slot-array barriers (parallel stores + min-poll), sticky alive guard.
// ---------------------------------------------------------------------------

#define B_    128
#define T_    1000
#define DIN_  64
#define E_    256
#define F_    64
#define H1_   80
#define DOUT_ 64
#define GEB   (E_*B_)
#define CLIPV 5.0f
#define LVMIN_ (-9.210340371976182f)

typedef unsigned short ushort_t;

__device__ __forceinline__ float sigm_(float x) { return 1.0f/(1.0f + expf(-x)); }
__device__ __forceinline__ float bfu_(ushort_t u) { return __uint_as_float(((unsigned)u) << 16); }

// Slot barrier / progress wait. slots[i*16] layout (64B stride per slot).
// If mine != nullptr, release-store val to it first. Waits until min over n
// slots >= target. alive: sticky guard flag (uniform across WG).
__device__ __forceinline__ void slot_wait(int* slots, int n, int* mine, int val,
                                          int target, volatile int* s_go, int& alive) {
  if (!alive) return;
  const int lane = threadIdx.x & 63;
  const int w = threadIdx.x >> 6;
  __syncthreads();
  if (mine != nullptr && threadIdx.x == 0)
    __hip_atomic_store(mine, val, __ATOMIC_RELEASE, __HIP_MEMORY_SCOPE_AGENT);
  int guard = 0;
  for (;;) {
    if (w == 0) {
      int mn = 0x7fffffff;
      for (int i = lane; i < n; i += 64) {
        const int v = __hip_atomic_load(&slots[i*16], __ATOMIC_RELAXED, __HIP_MEMORY_SCOPE_AGENT);
        mn = (v < mn) ? v : mn;
      }
      const unsigned long long ok = __ballot(mn >= target);
      if (lane == 0) *s_go = (ok == ~0ull) ? 1 : 0;
    }
    __syncthreads();
    const int go = *s_go;
    __syncthreads();
    if (go) break;
    if (++guard > 200000) { alive = 0; break; }
    __builtin_amdgcn_s_sleep(2);
  }
  __builtin_amdgcn_fence(__ATOMIC_ACQUIRE, "agent");
}

// Wait on a single flag location reaching target.
__device__ __forceinline__ void flag_wait(int* flag, int target,
                                          volatile int* s_go, int& alive) {
  if (!alive) return;
  const int w = threadIdx.x >> 6;
  __syncthreads();
  int guard = 0;
  for (;;) {
    if (w == 0) {
      const int v = __hip_atomic_load(flag, __ATOMIC_RELAXED, __HIP_MEMORY_SCOPE_AGENT);
      if ((threadIdx.x & 63) == 0) *s_go = (v >= target) ? 1 : 0;
    }
    __syncthreads();
    const int go = *s_go;
    __syncthreads();
    if (go) break;
    if (++guard > 200000) { alive = 0; break; }
    __builtin_amdgcn_s_sleep(2);
  }
  __builtin_amdgcn_fence(__ATOMIC_ACQUIRE, "agent");
}

// ------------------------- prep kernels ------------------------------------

// x[B][T][DIN] -> xT[T][B][DIN]
__global__ void k_transpose_x(const float* __restrict__ x, float* __restrict__ xT) {
  const int t = blockIdx.x;
  for (int idx = threadIdx.x; idx < B_*DIN_; idx += 256) {
    const int b = idx >> 6, k = idx & 63;
    xT[(size_t)t*(B_*DIN_) + idx] = x[(size_t)b*(T_*DIN_) + (size_t)t*DIN_ + k];
  }
}

// eps_u[B][T][2] -> epsT[T][2][B]
__global__ void k_transpose_eps(const float* __restrict__ eps_u, float* __restrict__ epsT) {
  const int t = blockIdx.x;
  const int o = threadIdx.x >> 7, b = threadIdx.x & 127;
  epsT[(size_t)t*2*B_ + o*B_ + b] = eps_u[(size_t)b*(T_*2) + t*2 + o];
}

// M[768][E] = con_wih[:,512:576] @ fac_w ; Wfb[768] = con_wih[:,512:576] @ fac_b
__global__ void k_composite(const float* __restrict__ conwih, const float* __restrict__ facw,
                            const float* __restrict__ facb, float* __restrict__ M,
                            float* __restrict__ Wfb) {
  const int idx = blockIdx.x*256 + threadIdx.x;   // 768*256
  const int j = idx >> 8, k = idx & 255;
  float acc = 0.0f;
  for (int ff = 0; ff < F_; ++ff)
    acc += conwih[(size_t)j*576 + 512 + ff] * facw[(size_t)ff*E_ + k];
  M[(size_t)j*E_ + k] = acc;
  if (k == 0) {
    float s = 0.0f;
    for (int ff = 0; ff < F_; ++ff) s += conwih[(size_t)j*576 + 512 + ff] * facb[ff];
    Wfb[j] = s;
  }
}

// ------------------------- encoder -----------------------------------------

struct EncArgs {
  const float* xT;             // [T][B][DIN]
  const float* wih[4];
  const float* whh[4];
  const float* bih[4];
  const float* bhh[4];
  float* hT;                   // [4][2][B][E]
  __hip_bfloat16* efS;         // [T][E][B]
  __hip_bfloat16* ebS;
  int* arr;                    // 4*64 slots, stride 16
};

__global__ __launch_bounds__(256, 1) void k_encoder(EncArgs a) {
  __shared__ float s_we[7680];   // 8 local j x [wx r|z|n (64 ea) | wh r|z|n (256 ea)]
  __shared__ int s_goE;
  const int chain = blockIdx.x >> 6;
  const int rnk   = blockIdx.x & 63;
  const int jjg   = rnk >> 1;
  const int bg    = rnk & 1;
  const int lane  = threadIdx.x & 63;
  const int w     = threadIdx.x >> 6;
  const int b     = bg*64 + lane;

  const float* wih = a.wih[chain];
  const float* whh = a.whh[chain];
  const float* bih = a.bih[chain];
  const float* bhh = a.bhh[chain];
  float* hTc = a.hT + (size_t)chain*2*GEB;
  int* slots = a.arr + chain*1024;
  int* myslot = slots + rnk*16;
  const bool bwd = (chain >= 2);
  __hip_bfloat16* st = (chain == 1) ? a.efS : (chain == 3 ? a.ebS : nullptr);

  for (int idx = threadIdx.x; idx < 7680; idx += 256) {
    const int jl = idx / 960, r = idx % 960;
    const int jj = jjg*8 + jl;
    float v;
    if (r < 192) { const int gate = r/64, c = r%64;
      v = wih[(size_t)(gate*E_ + jj)*DIN_ + c];
    } else { const int rh = r - 192; const int gate = rh/256, c = rh%256;
      v = whh[(size_t)(gate*E_ + jj)*E_ + c];
    }
    s_we[idx] = v;
  }
  __syncthreads();

  const int j0l = 2*w, j1l = 2*w + 1;
  const int j0 = jjg*8 + j0l, j1 = j0 + 1;

  const float brz0 = bih[j0] + bhh[j0];
  const float brz1 = bih[j1] + bhh[j1];
  const float bz0  = bih[E_+j0] + bhh[E_+j0];
  const float bz1  = bih[E_+j1] + bhh[E_+j1];
  const float bni0 = bih[2*E_+j0], bni1 = bih[2*E_+j1];
  const float bnh0 = bhh[2*E_+j0], bnh1 = bhh[2*E_+j1];

  const float4* wr0x = (const float4*)(s_we + j0l*960);
  const float4* wz0x = (const float4*)(s_we + j0l*960 + 64);
  const float4* wn0x = (const float4*)(s_we + j0l*960 + 128);
  const float4* wr0h = (const float4*)(s_we + j0l*960 + 192);
  const float4* wz0h = (const float4*)(s_we + j0l*960 + 448);
  const float4* wn0h = (const float4*)(s_we + j0l*960 + 704);
  const float4* wr1x = (const float4*)(s_we + j1l*960);
  const float4* wz1x = (const float4*)(s_we + j1l*960 + 64);
  const float4* wn1x = (const float4*)(s_we + j1l*960 + 128);
  const float4* wr1h = (const float4*)(s_we + j1l*960 + 192);
  const float4* wz1h = (const float4*)(s_we + j1l*960 + 448);
  const float4* wn1h = (const float4*)(s_we + j1l*960 + 704);

  int alive = 1;
  int p = 0;
  for (int t = 0; t < T_; ++t) {
    const int tt = bwd ? (T_-1-t) : t;
    const float* xp = a.xT + (size_t)tt*(B_*DIN_) + (size_t)b*DIN_;
    const float* hp = hTc + (size_t)p*GEB + (size_t)b*E_;
    float ar0=0,az0=0,an0=0,ah0=0, ar1=0,az1=0,an1=0,ah1=0;
    for (int k4 = 0; k4 < 16; ++k4) {
      const float4 x4 = *(const float4*)(xp + 4*k4);
      float4 v;
      v = wr0x[k4]; ar0 += v.x*x4.x + v.y*x4.y + v.z*x4.z + v.w*x4.w;
      v = wz0x[k4]; az0 += v.x*x4.x + v.y*x4.y + v.z*x4.z + v.w*x4.w;
      v = wn0x[k4]; an0 += v.x*x4.x + v.y*x4.y + v.z*x4.z + v.w*x4.w;
      v = wr1x[k4]; ar1 += v.x*x4.x + v.y*x4.y + v.z*x4.z + v.w*x4.w;
      v = wz1x[k4]; az1 += v.x*x4.x + v.y*x4.y + v.z*x4.z + v.w*x4.w;
      v = wn1x[k4]; an1 += v.x*x4.x + v.y*x4.y + v.z*x4.z + v.w*x4.w;
    }
    for (int k4 = 0; k4 < 64; ++k4) {
      const float4 h4 = *(const float4*)(hp + 4*k4);
      float4 v;
      v = wr0h[k4]; ar0 += v.x*h4.x + v.y*h4.y + v.z*h4.z + v.w*h4.w;
      v = wz0h[k4]; az0 += v.x*h4.x + v.y*h4.y + v.z*h4.z + v.w*h4.w;
      v = wn0h[k4]; ah0 += v.x*h4.x + v.y*h4.y + v.z*h4.z + v.w*h4.w;
      v = wr1h[k4]; ar1 += v.x*h4.x + v.y*h4.y + v.z*h4.z + v.w*h4.w;
      v = wz1h[k4]; az1 += v.x*h4.x + v.y*h4.y + v.z*h4.z + v.w*h4.w;
      v = wn1h[k4]; ah1 += v.x*h4.x + v.y*h4.y + v.z*h4.z + v.w*h4.w;
    }
    const float hprev0 = hp[j0];
    const float hprev1 = hp[j1];
    const float r0 = sigm_(ar0 + brz0);
    const float z0 = sigm_(az0 + bz0);
    const float n0 = tanhf(an0 + bni0 + r0*(ah0 + bnh0));
    const float h0n = fminf((1.0f - z0)*n0 + z0*hprev0, CLIPV);
    const float r1 = sigm_(ar1 + brz1);
    const float z1 = sigm_(az1 + bz1);
    const float n1 = tanhf(an1 + bni1 + r1*(ah1 + bnh1));
    const float h1n = fminf((1.0f - z1)*n1 + z1*hprev1, CLIPV);
    float* hq = hTc + (size_t)(p^1)*GEB + (size_t)b*E_;
    hq[j0] = h0n;
    hq[j1] = h1n;
    if (st) {
      st[(size_t)tt*GEB + (size_t)j0*B_ + b] = __float2bfloat16(h0n);
      st[(size_t)tt*GEB + (size_t)j1*B_ + b] = __float2bfloat16(h1n);
    }
    slot_wait(slots, 64, myslot, t+1, t+1, &s_goE, alive);
    p ^= 1;
  }
}

// ------------------------- g0 sample ----------------------------------------

__global__ void k_g0(const float* __restrict__ hT, const float* __restrict__ g0mw,
                     const float* __restrict__ g0mb, const float* __restrict__ g0vw,
                     const float* __restrict__ g0vb, const float* __restrict__ eps_g0,
                     float* __restrict__ gT) {
  const int b = threadIdx.x & 127;
  const int half = threadIdx.x >> 7;
  const int kout = blockIdx.x*2 + half;
  const float* hf = hT + (size_t)b*E_;             // chain0 (egf), buffer 0
  const float* hb = hT + 4*GEB + (size_t)b*E_;     // chain2 (egb), buffer 0
  const float* mrow = g0mw + (size_t)kout*512;
  const float* vrow = g0vw + (size_t)kout*512;
  float dm = 0.0f, dv = 0.0f;
  for (int k = 0; k < E_; ++k) {
    const float hv = hf[k];
    dm += mrow[k]*hv; dv += vrow[k]*hv;
  }
  for (int k = 0; k < E_; ++k) {
    const float hv = hb[k];
    dm += mrow[256+k]*hv; dv += vrow[256+k]*hv;
  }
  const float lv = fmaxf(dv + g0vb[kout], LVMIN_);
  gT[(size_t)b*E_ + kout] = eps_g0[(size_t)b*E_ + kout]*expf(0.5f*lv) + dm + g0mb[kout];
}

// ------------------------- generator (3 roles) -------------------------------

struct GenAll {
  const float* M; const float* conwhh; const float* genwhh;
  const float* conbih; const float* conbhh; const float* Wfb;
  const float* genwih; const float* genbih; const float* genbhh;
  const float* umw; const float* umb; const float* uvw; const float* uvb;
  const float* epsT;          // [T][2][B]
  const float* conwih;        // [768][576]
  const __hip_bfloat16* efS;  // [T][E][B]
  const __hip_bfloat16* ebS;
  __hip_bfloat16* ge;         // ring [128][768][B]
  float* gT; float* cT;       // [2][B][E]
  const float* facw; const float* facb;
  const float* f1w; const float* f1b;
  const float* clw; const float* clb;
  float* out;                 // [B][T][DOUT]
  int* arr_main;              // 160 slots stride 16
  int* flags;                 // 128 slots stride 16
};

__global__ __launch_bounds__(256, 1) void k_generator(GenAll a) {
  __shared__ __align__(16) unsigned char s_raw[60416];
  const int lane = threadIdx.x & 63;
  const int w = threadIdx.x >> 6;

  if (blockIdx.x < 128) {
    // ======================= consumer =======================
    float* s_w   = (float*)s_raw;              // 4*2304 f32 = 36864 B
    float* s_uwT = (float*)(s_raw + 36864);    // [k][4]     = 4096 B
    float* s_up  = (float*)(s_raw + 40960);    // [4][256]   = 4096 B
    volatile int* s_go = (volatile int*)(s_raw + 45056);
    const int jjgq = blockIdx.x >> 1;
    const int bg = blockIdx.x & 1;
    const int b = bg*64 + lane;

    for (int idx = threadIdx.x; idx < 9216; idx += 256) {
      const int jl = idx / 2304, r = idx % 2304;
      const int jj = jjgq*4 + jl;
      const int sec = r / 768, rr = r % 768, gate = rr >> 8, c = rr & 255;
      const float* src = (sec == 0) ? a.M : (sec == 1 ? a.conwhh : a.genwhh);
      s_w[idx] = src[(size_t)(gate*E_ + jj)*E_ + c];
    }
    for (int idx = threadIdx.x; idx < 1024; idx += 256) {
      const int k = idx >> 2, q = idx & 3;
      s_uwT[idx] = (q < 2) ? a.umw[q*E_ + k] : a.uvw[(q-2)*E_ + k];
    }
    __syncthreads();

    const int j = jjgq*4 + w;
    const float* base = s_w + w*2304;
    const float4* Mr  = (const float4*)(base);
    const float4* Mz  = (const float4*)(base + 256);
    const float4* Mn  = (const float4*)(base + 512);
    const float4* Whr = (const float4*)(base + 768);
    const float4* Whz = (const float4*)(base + 1024);
    const float4* Whn = (const float4*)(base + 1280);
    const float4* Gwr = (const float4*)(base + 1536);
    const float4* Gwz = (const float4*)(base + 1792);
    const float4* Gwn = (const float4*)(base + 2048);

    const float brz_c = a.conbih[j] + a.conbhh[j] + a.Wfb[j];
    const float bz_c  = a.conbih[E_+j] + a.conbhh[E_+j] + a.Wfb[E_+j];
    const float bni_c = a.conbih[2*E_+j] + a.Wfb[2*E_+j];
    const float bnh_c = a.conbhh[2*E_+j];
    const float gur0 = a.genwih[j*2],        gur1 = a.genwih[j*2+1];
    const float guz0 = a.genwih[(E_+j)*2],   guz1 = a.genwih[(E_+j)*2+1];
    const float gun0 = a.genwih[(2*E_+j)*2], gun1 = a.genwih[(2*E_+j)*2+1];
    const float brz_g = a.genbih[j] + a.genbhh[j];
    const float bz_g  = a.genbih[E_+j] + a.genbhh[E_+j];
    const float bni_g = a.genbih[2*E_+j];
    const float bnh_g = a.genbhh[2*E_+j];
    const float umb0 = a.umb[0], umb1 = a.umb[1];
    const float uvb0 = a.uvb[0], uvb1 = a.uvb[1];

    int* myslot = a.arr_main + blockIdx.x*16;
    int alive = 1;
    for (int t = 0; t < T_; ++t) {
      const float* gpb = a.gT + (size_t)(t&1)*GEB + (size_t)b*E_;
      const float* cpb = a.cT + (size_t)(t&1)*GEB + (size_t)b*E_;
      float ar=0,az=0,an=0,ah=0,gr=0,gz=0,gh=0;
      for (int k4 = 0; k4 < 64; ++k4) {
        const float4 g4 = *(const float4*)(gpb + 4*k4);
        const float4 c4 = *(const float4*)(cpb + 4*k4);
        float4 v;
        v = Mr[k4];  ar += v.x*g4.x + v.y*g4.y + v.z*g4.z + v.w*g4.w;
        v = Mz[k4];  az += v.x*g4.x + v.y*g4.y + v.z*g4.z + v.w*g4.w;
        v = Mn[k4];  an += v.x*g4.x + v.y*g4.y + v.z*g4.z + v.w*g4.w;
        v = Gwr[k4]; gr += v.x*g4.x + v.y*g4.y + v.z*g4.z + v.w*g4.w;
        v = Gwz[k4]; gz += v.x*g4.x + v.y*g4.y + v.z*g4.z + v.w*g4.w;
        v = Gwn[k4]; gh += v.x*g4.x + v.y*g4.y + v.z*g4.z + v.w*g4.w;
        v = Whr[k4]; ar += v.x*c4.x + v.y*c4.y + v.z*c4.z + v.w*c4.w;
        v = Whz[k4]; az += v.x*c4.x + v.y*c4.y + v.z*c4.z + v.w*c4.w;
        v = Whn[k4]; ah += v.x*c4.x + v.y*c4.y + v.z*c4.z + v.w*c4.w;
      }
      // wait for producers of ge[t], then add its 3 contributions
      flag_wait(a.flags + (t & 127)*16, 48*((t >> 7) + 1), s_go, alive);
      const ushort_t* gep = (const ushort_t*)a.ge + (size_t)(t & 127)*(768*B_);
      ar += bfu_(gep[(size_t)j*B_ + b]);
      az += bfu_(gep[(size_t)(E_+j)*B_ + b]);
      an += bfu_(gep[(size_t)(2*E_+j)*B_ + b]);
      const float cprev = cpb[j];
      const float r = sigm_(ar + brz_c);
      const float z = sigm_(az + bz_c);
      const float n = tanhf(an + bni_c + r*(ah + bnh_c));
      const float cn = fminf((1.0f - z)*n + z*cprev, CLIPV);
      a.cT[(size_t)((t+1)&1)*GEB + (size_t)b*E_ + j] = cn;
      slot_wait(a.arr_main, 160, myslot, 2*t+1, 2*t+1, s_go, alive);

      // ---- u partials over this wave's k-quarter of fresh c ----
      const float* cq = a.cT + (size_t)((t+1)&1)*GEB + (size_t)b*E_ + w*64;
      float p0=0,p1=0,p2=0,p3=0;
      for (int kk = 0; kk < 16; ++kk) {
        const float4 c4 = *(const float4*)(cq + 4*kk);
        const float4 w0 = *(const float4*)(s_uwT + (w*64 + 4*kk + 0)*4);
        const float4 w1 = *(const float4*)(s_uwT + (w*64 + 4*kk + 1)*4);
        const float4 w2 = *(const float4*)(s_uwT + (w*64 + 4*kk + 2)*4);
        const float4 w3 = *(const float4*)(s_uwT + (w*64 + 4*kk + 3)*4);
        p0 += w0.x*c4.x + w1.x*c4.y + w2.x*c4.z + w3.x*c4.w;
        p1 += w0.y*c4.x + w1.y*c4.y + w2.y*c4.z + w3.y*c4.w;
        p2 += w0.z*c4.x + w1.z*c4.y + w2.z*c4.z + w3.z*c4.w;
        p3 += w0.w*c4.x + w1.w*c4.y + w2.w*c4.z + w3.w*c4.w;
      }
      s_up[0*256 + threadIdx.x] = p0;
      s_up[1*256 + threadIdx.x] = p1;
      s_up[2*256 + threadIdx.x] = p2;
      s_up[3*256 + threadIdx.x] = p3;
      __syncthreads();
      const float m0 = s_up[lane] + s_up[64+lane] + s_up[128+lane] + s_up[192+lane] + umb0;
      const float m1 = s_up[256+lane] + s_up[320+lane] + s_up[384+lane] + s_up[448+lane] + umb1;
      const float lv0 = fmaxf(s_up[512+lane] + s_up[576+lane] + s_up[640+lane] + s_up[704+lane] + uvb0, LVMIN_);
      const float lv1 = fmaxf(s_up[768+lane] + s_up[832+lane] + s_up[896+lane] + s_up[960+lane] + uvb1, LVMIN_);
      const float eps0 = a.epsT[(size_t)t*256 + b];
      const float eps1 = a.epsT[(size_t)t*256 + 128 + b];
      const float u0 = eps0*expf(0.5f*lv0) + m0;
      const float u1 = eps1*expf(0.5f*lv1) + m1;

      const float rg = sigm_(gr + gur0*u0 + gur1*u1 + brz_g);
      const float zg = sigm_(gz + guz0*u0 + guz1*u1 + bz_g);
      const float ng = tanhf(gun0*u0 + gun1*u1 + bni_g + rg*(gh + bnh_g));
      const float gprev = gpb[j];
      const float gn = fminf((1.0f - zg)*ng + zg*gprev, CLIPV);
      a.gT[(size_t)((t+1)&1)*GEB + (size_t)b*E_ + j] = gn;
      slot_wait(a.arr_main, 160, myslot, 2*t+2, 2*t+2, s_go, alive);
    }
  } else if (blockIdx.x < 224) {
    // ======================= producer =======================
    float* s_wp = (float*)s_raw;                   // [512][16] f32 = 32768 B
    volatile int* s_go = (volatile int*)(s_raw + 32768);
    const int pid = blockIdx.x - 128;
    const int tile = pid % 48, phase = pid / 48;
    const int r0 = tile*16;
    for (int idx = threadIdx.x; idx < 8192; idx += 256) {
      const int k = idx >> 4, rl = idx & 15;
      s_wp[idx] = a.conwih[(size_t)(r0 + rl)*576 + k];
    }
    __syncthreads();
    const int half = w & 1, rq = w >> 1;
    const int b = half*64 + lane, rl0 = rq*8;
    int alive = 1;
    for (int t = phase; t < T_; t += 2) {
      if (t >= 128)   // don't clobber ring slot until consumers are past t-128
        slot_wait(a.arr_main, 160, nullptr, 0, 2*(t-126)+1, s_go, alive);
      float acc[8] = {0,0,0,0,0,0,0,0};
      const ushort_t* efp = (const ushort_t*)a.efS + (size_t)t*GEB + b;
      const ushort_t* ebp = (const ushort_t*)a.ebS + (size_t)t*GEB + b;
      for (int k = 0; k < 256; ++k) {
        const float ev = bfu_(efp[(size_t)k*B_]);
        const float4 w0 = *(const float4*)(s_wp + k*16 + rl0);
        const float4 w1 = *(const float4*)(s_wp + k*16 + rl0 + 4);
        acc[0]+=w0.x*ev; acc[1]+=w0.y*ev; acc[2]+=w0.z*ev; acc[3]+=w0.w*ev;
        acc[4]+=w1.x*ev; acc[5]+=w1.y*ev; acc[6]+=w1.z*ev; acc[7]+=w1.w*ev;
      }
      for (int k = 0; k < 256; ++k) {
        const float ev = bfu_(ebp[(size_t)k*B_]);
        const float4 w0 = *(const float4*)(s_wp + (256+k)*16 + rl0);
        const float4 w1 = *(const float4*)(s_wp + (256+k)*16 + rl0 + 4);
        acc[0]+=w0.x*ev; acc[1]+=w0.y*ev; acc[2]+=w0.z*ev; acc[3]+=w0.w*ev;
        acc[4]+=w1.x*ev; acc[5]+=w1.y*ev; acc[6]+=w1.z*ev; acc[7]+=w1.w*ev;
      }
      __hip_bfloat16* gesl = a.ge + (size_t)(t & 127)*(768*B_) + (size_t)(r0 + rl0)*B_ + b;
      for (int i = 0; i < 8; ++i) gesl[(size_t)i*B_] = __float2bfloat16(acc[i]);
      __syncthreads();
      if (threadIdx.x == 0)
        __hip_atomic_fetch_add(a.flags + (t & 127)*16, 1, __ATOMIC_RELEASE, __HIP_MEMORY_SCOPE_AGENT);
    }
  } else {
    // ======================= output MLP =======================
    __hip_bfloat16* s_fw  = (__hip_bfloat16*)s_raw;              // [256][64] 32768 B
    __hip_bfloat16* s_f1T = (__hip_bfloat16*)(s_raw + 32768);    // [64][80] 10240 B
    __hip_bfloat16* s_clT = (__hip_bfloat16*)(s_raw + 43008);    // [80][64] 10240 B
    float* s_g  = (float*)(s_raw + 53248);                       // [4][256] 4096 B
    float* s_f  = (float*)(s_raw + 57344);                       // [4][64]  1024 B
    float* s_h1 = (float*)(s_raw + 58368);                       // [4][80]  1280 B
    volatile int* s_go = (volatile int*)(s_raw + 59648);
    for (int idx = threadIdx.x; idx < 16384; idx += 256) {
      const int k = idx >> 6, fd = idx & 63;
      s_fw[idx] = __float2bfloat16(a.facw[(size_t)fd*E_ + k]);
    }
    for (int idx = threadIdx.x; idx < 5120; idx += 256) {
      const int kf = idx / H1_, hd = idx % H1_;
      s_f1T[idx] = __float2bfloat16(a.f1w[(size_t)hd*64 + kf]);
    }
    for (int idx = threadIdx.x; idx < 5120; idx += 256) {
      const int kh = idx >> 6, od = idx & 63;
      s_clT[idx] = __float2bfloat16(a.clw[(size_t)od*H1_ + kh]);
    }
    __syncthreads();
    const int oid = blockIdx.x - 224;
    const int b = oid*4 + w;
    const float facb_l = a.facb[lane];
    const float f1b_a  = a.f1b[lane];
    const float f1b_b  = (lane < 16) ? a.f1b[64 + lane] : 0.0f;
    const float clb_l  = a.clb[lane];
    int* myslot = a.arr_main + (128 + oid)*16;
    int alive = 1;
    for (int t = 0; t <= T_; ++t) {
      const int tt = t - 1;
      if (tt >= 0) {
        const float* gq = a.gT + (size_t)((tt+1)&1)*GEB + (size_t)b*E_;
        *(float4*)(s_g + w*256 + lane*4) = *(const float4*)(gq + lane*4);
        float f = facb_l;
        for (int k = 0; k < 256; ++k)
          f += __bfloat162float(s_fw[k*64 + lane]) * s_g[w*256 + k];
        s_f[w*64 + lane] = f;
        float h1a = f1b_a, h1b = f1b_b;
        for (int kf = 0; kf < 64; ++kf) {
          const float fv = s_f[w*64 + kf];
          h1a += __bfloat162float(s_f1T[kf*H1_ + lane]) * fv;
          if (lane < 16) h1b += __bfloat162float(s_f1T[kf*H1_ + 64 + lane]) * fv;
        }
        s_h1[w*H1_ + lane] = fmaxf(h1a, 0.0f);
        if (lane < 16) s_h1[w*H1_ + 64 + lane] = fmaxf(h1b, 0.0f);
        float o = clb_l;
        for (int kh = 0; kh < H1_; ++kh)
          o += __bfloat162float(s_clT[kh*64 + lane]) * s_h1[w*H1_ + kh];
        a.out[((size_t)b*T_ + tt)*DOUT_ + lane] = o;
      }
      if (t == T_) break;
      slot_wait(a.arr_main, 160, myslot, 2*t+1, 2*t+1, s_go, alive);
      slot_wait(a.arr_main, 160, myslot, 2*t+2, 2*t+2, s_go, alive);
    }
  }
}

// ------------------------- host launcher ------------------------------------

extern "C" void kernel_launch(void* const* d_in, const int* in_sizes, int n_in,
                              void* d_out, int out_size, void* d_ws, size_t ws_size,
                              hipStream_t stream) {
  const float* x      = (const float*)d_in[0];
  const float* eps_g0 = (const float*)d_in[1];
  const float* eps_u  = (const float*)d_in[2];
  const float* egf_wih = (const float*)d_in[3],  *egf_whh = (const float*)d_in[4];
  const float* egf_bih = (const float*)d_in[5],  *egf_bhh = (const float*)d_in[6];
  const float* egb_wih = (const float*)d_in[7],  *egb_whh = (const float*)d_in[8];
  const float* egb_bih = (const float*)d_in[9],  *egb_bhh = (const float*)d_in[10];
  const float* ecf_wih = (const float*)d_in[11], *ecf_whh = (const float*)d_in[12];
  const float* ecf_bih = (const float*)d_in[13], *ecf_bhh = (const float*)d_in[14];
  const float* ecb_wih = (const float*)d_in[15], *ecb_whh = (const float*)d_in[16];
  const float* ecb_bih = (const float*)d_in[17], *ecb_bhh = (const float*)d_in[18];
  const float* con_wih = (const float*)d_in[19], *con_whh = (const float*)d_in[20];
  const float* con_bih = (const float*)d_in[21], *con_bhh = (const float*)d_in[22];
  const float* gen_wih = (const float*)d_in[23], *gen_whh = (const float*)d_in[24];
  const float* gen_bih = (const float*)d_in[25], *gen_bhh = (const float*)d_in[26];
  const float* g0m_w = (const float*)d_in[27], *g0m_b = (const float*)d_in[28];
  const float* g0v_w = (const float*)d_in[29], *g0v_b = (const float*)d_in[30];
  const float* um_w = (const float*)d_in[31], *um_b = (const float*)d_in[32];
  const float* uv_w = (const float*)d_in[33], *uv_b = (const float*)d_in[34];
  const float* fac_w = (const float*)d_in[35], *fac_b = (const float*)d_in[36];
  const float* f1_w = (const float*)d_in[37], *f1_b = (const float*)d_in[38];
  const float* cl_w = (const float*)d_in[39], *cl_b = (const float*)d_in[40];
  float* out = (float*)d_out;
  (void)ws_size; (void)in_sizes; (void)n_in; (void)out_size;

  // Workspace layout — total 167,262,208 B <= proven 167,297,024 B (round 0).
  // ge ring (25,165,824 B) aliases xT (dead after encoder).
  char* ws = (char*)d_ws;
  const size_t o_xT   = 0;             // f32 [T][B][DIN]        32,768,000
  const size_t o_ge   = 0;             // bf16 [128][768][B]     25,165,824 (alias)
  const size_t o_efS  = 32768000ul;    // bf16 [T][E][B]         65,536,000
  const size_t o_ebS  = 98304000ul;    //                        65,536,000
  const size_t o_epsT = 163840000ul;   // f32 [T][2][B]           1,024,000
  const size_t o_M    = 164864000ul;   // f32 [768][E]              786,432
  const size_t o_Wfb  = 165650432ul;   // f32 [768]                   4,096
  const size_t o_hT   = 165654528ul;   // f32 [4][2][B][E]        1,048,576
  const size_t o_gT   = 166703104ul;   // f32 [2][B][E]             262,144
  const size_t o_cT   = 166965248ul;   //                           262,144
  const size_t o_ctl  = 167227392ul;   // int slots                  34,816

  float* xT = (float*)(ws + o_xT);
  __hip_bfloat16* ge = (__hip_bfloat16*)(ws + o_ge);
  __hip_bfloat16* efS = (__hip_bfloat16*)(ws + o_efS);
  __hip_bfloat16* ebS = (__hip_bfloat16*)(ws + o_ebS);
  float* epsT = (float*)(ws + o_epsT);
  float* M = (float*)(ws + o_M);
  float* Wfb = (float*)(ws + o_Wfb);
  float* hT = (float*)(ws + o_hT);
  float* gT = (float*)(ws + o_gT);
  float* cT = (float*)(ws + o_cT);
  int* ctl = (int*)(ws + o_ctl);
  int* arr_main = ctl;           // 160 slots * 16 ints
  int* flags    = ctl + 2560;    // 128 slots * 16 ints
  int* arr_enc  = ctl + 4608;    // 4*64 slots * 16 ints

  // zero h/g/c state + all control slots (ws is poisoned 0xAA each launch)
  hipMemsetAsync(ws + o_hT, 0, 167262208ul - o_hT, stream);

  k_transpose_x<<<T_, 256, 0, stream>>>(x, xT);
  k_transpose_eps<<<T_, 256, 0, stream>>>(eps_u, epsT);
  k_composite<<<768, 256, 0, stream>>>(con_wih, fac_w, fac_b, M, Wfb);

  EncArgs ea;
  ea.xT = xT;
  ea.wih[0] = egf_wih; ea.whh[0] = egf_whh; ea.bih[0] = egf_bih; ea.bhh[0] = egf_bhh;
  ea.wih[1] = ecf_wih; ea.whh[1] = ecf_whh; ea.bih[1] = ecf_bih; ea.bhh[1] = ecf_bhh;
  ea.wih[2] = egb_wih; ea.whh[2] = egb_whh; ea.bih[2] = egb_bih; ea.bhh[2] = egb_bhh;
  ea.wih[3] = ecb_wih; ea.whh[3] = ecb_whh; ea.bih[3] = ecb_bih; ea.bhh[3] = ecb_bhh;
  ea.hT = hT; ea.efS = efS; ea.ebS = ebS; ea.arr = arr_enc;
  k_encoder<<<256, 256, 0, stream>>>(ea);

  k_g0<<<128, 256, 0, stream>>>(hT, g0m_w, g0m_b, g0v_w, g0v_b, eps_g0, gT);

  GenAll ga;
  ga.M = M; ga.conwhh = con_whh; ga.genwhh = gen_whh;
  ga.conbih = con_bih; ga.conbhh = con_bhh; ga.Wfb = Wfb;
  ga.genwih = gen_wih; ga.genbih = gen_bih; ga.genbhh = gen_bhh;
  ga.umw = um_w; ga.umb = um_b; ga.uvw = uv_w; ga.uvb = uv_b;
  ga.epsT = epsT; ga.conwih = con_wih;
  ga.efS = efS; ga.ebS = ebS; ga.ge = ge;
  ga.gT = gT; ga.cT = cT;
  ga.facw = fac_w; ga.facb = fac_b;
  ga.f1w = f1_w; ga.f1b = f1_b; ga.clw = cl_w; ga.clb = cl_b;
  ga.out = out;
  ga.arr_main = arr_main; ga.flags = flags;
  k_generator<<<256, 256, 0, stream>>>(ga);
}

// Round 4
// 76269.348 us; speedup vs baseline: 1.2164x; 1.0025x over previous
//
#include <hip/hip_runtime.h>
#include <hip/hip_bf16.h>
#include <stdint.h>
#include <stddef.h>

// ---------------------------------------------------------------------------
// LFADS forward on MI355X — round 3.
// ROUND-2 POST-MORTEM: the generator's 73-84 ms was a sync-timeout artifact:
// hipMemsetAsync zeroed only 4 KB of the 34.8 KB control region, leaving the
// producer->consumer `flags` array 0xAA-poisoned (negative forever, since it
// is only fetch_add-ed, never stored). Every consumer's first flag_wait spun
// to the 200k guard (~40-90 ms), tripped alive=0, and the kernel free-ran.
// FIX (only change this round): memset the ENTIRE hT..ctl region (1,607,680B)
// so the slot/flag protocol actually runs.
// ---------------------------------------------------------------------------

#define B_    128
#define T_    1000
#define DIN_  64
#define E_    256
#define F_    64
#define H1_   80
#define DOUT_ 64
#define GEB   (E_*B_)
#define CLIPV 5.0f
#define LVMIN_ (-9.210340371976182f)

typedef unsigned short ushort_t;

__device__ __forceinline__ float sigm_(float x) { return 1.0f/(1.0f + expf(-x)); }
__device__ __forceinline__ float bfu_(ushort_t u) { return __uint_as_float(((unsigned)u) << 16); }

// Slot barrier / progress wait. slots[i*16] layout (64B stride per slot).
// If mine != nullptr, release-store val to it first. Waits until min over n
// slots >= target. alive: sticky guard flag (uniform across WG).
__device__ __forceinline__ void slot_wait(int* slots, int n, int* mine, int val,
                                          int target, volatile int* s_go, int& alive) {
  if (!alive) return;
  const int lane = threadIdx.x & 63;
  const int w = threadIdx.x >> 6;
  __syncthreads();
  if (mine != nullptr && threadIdx.x == 0)
    __hip_atomic_store(mine, val, __ATOMIC_RELEASE, __HIP_MEMORY_SCOPE_AGENT);
  int guard = 0;
  for (;;) {
    if (w == 0) {
      int mn = 0x7fffffff;
      for (int i = lane; i < n; i += 64) {
        const int v = __hip_atomic_load(&slots[i*16], __ATOMIC_RELAXED, __HIP_MEMORY_SCOPE_AGENT);
        mn = (v < mn) ? v : mn;
      }
      const unsigned long long ok = __ballot(mn >= target);
      if (lane == 0) *s_go = (ok == ~0ull) ? 1 : 0;
    }
    __syncthreads();
    const int go = *s_go;
    __syncthreads();
    if (go) break;
    if (++guard > 200000) { alive = 0; break; }
    __builtin_amdgcn_s_sleep(2);
  }
  __builtin_amdgcn_fence(__ATOMIC_ACQUIRE, "agent");
}

// Wait on a single flag location reaching target.
__device__ __forceinline__ void flag_wait(int* flag, int target,
                                          volatile int* s_go, int& alive) {
  if (!alive) return;
  const int w = threadIdx.x >> 6;
  __syncthreads();
  int guard = 0;
  for (;;) {
    if (w == 0) {
      const int v = __hip_atomic_load(flag, __ATOMIC_RELAXED, __HIP_MEMORY_SCOPE_AGENT);
      if ((threadIdx.x & 63) == 0) *s_go = (v >= target) ? 1 : 0;
    }
    __syncthreads();
    const int go = *s_go;
    __syncthreads();
    if (go) break;
    if (++guard > 200000) { alive = 0; break; }
    __builtin_amdgcn_s_sleep(2);
  }
  __builtin_amdgcn_fence(__ATOMIC_ACQUIRE, "agent");
}

// ------------------------- prep kernels ------------------------------------

// x[B][T][DIN] -> xT[T][B][DIN]
__global__ void k_transpose_x(const float* __restrict__ x, float* __restrict__ xT) {
  const int t = blockIdx.x;
  for (int idx = threadIdx.x; idx < B_*DIN_; idx += 256) {
    const int b = idx >> 6, k = idx & 63;
    xT[(size_t)t*(B_*DIN_) + idx] = x[(size_t)b*(T_*DIN_) + (size_t)t*DIN_ + k];
  }
}

// eps_u[B][T][2] -> epsT[T][2][B]
__global__ void k_transpose_eps(const float* __restrict__ eps_u, float* __restrict__ epsT) {
  const int t = blockIdx.x;
  const int o = threadIdx.x >> 7, b = threadIdx.x & 127;
  epsT[(size_t)t*2*B_ + o*B_ + b] = eps_u[(size_t)b*(T_*2) + t*2 + o];
}

// M[768][E] = con_wih[:,512:576] @ fac_w ; Wfb[768] = con_wih[:,512:576] @ fac_b
__global__ void k_composite(const float* __restrict__ conwih, const float* __restrict__ facw,
                            const float* __restrict__ facb, float* __restrict__ M,
                            float* __restrict__ Wfb) {
  const int idx = blockIdx.x*256 + threadIdx.x;   // 768*256
  const int j = idx >> 8, k = idx & 255;
  float acc = 0.0f;
  for (int ff = 0; ff < F_; ++ff)
    acc += conwih[(size_t)j*576 + 512 + ff] * facw[(size_t)ff*E_ + k];
  M[(size_t)j*E_ + k] = acc;
  if (k == 0) {
    float s = 0.0f;
    for (int ff = 0; ff < F_; ++ff) s += conwih[(size_t)j*576 + 512 + ff] * facb[ff];
    Wfb[j] = s;
  }
}

// ------------------------- encoder -----------------------------------------

struct EncArgs {
  const float* xT;             // [T][B][DIN]
  const float* wih[4];
  const float* whh[4];
  const float* bih[4];
  const float* bhh[4];
  float* hT;                   // [4][2][B][E]
  __hip_bfloat16* efS;         // [T][E][B]
  __hip_bfloat16* ebS;
  int* arr;                    // 4*64 slots, stride 16
};

__global__ __launch_bounds__(256, 1) void k_encoder(EncArgs a) {
  __shared__ float s_we[7680];   // 8 local j x [wx r|z|n (64 ea) | wh r|z|n (256 ea)]
  __shared__ int s_goE;
  const int chain = blockIdx.x >> 6;
  const int rnk   = blockIdx.x & 63;
  const int jjg   = rnk >> 1;
  const int bg    = rnk & 1;
  const int lane  = threadIdx.x & 63;
  const int w     = threadIdx.x >> 6;
  const int b     = bg*64 + lane;

  const float* wih = a.wih[chain];
  const float* whh = a.whh[chain];
  const float* bih = a.bih[chain];
  const float* bhh = a.bhh[chain];
  float* hTc = a.hT + (size_t)chain*2*GEB;
  int* slots = a.arr + chain*1024;
  int* myslot = slots + rnk*16;
  const bool bwd = (chain >= 2);
  __hip_bfloat16* st = (chain == 1) ? a.efS : (chain == 3 ? a.ebS : nullptr);

  for (int idx = threadIdx.x; idx < 7680; idx += 256) {
    const int jl = idx / 960, r = idx % 960;
    const int jj = jjg*8 + jl;
    float v;
    if (r < 192) { const int gate = r/64, c = r%64;
      v = wih[(size_t)(gate*E_ + jj)*DIN_ + c];
    } else { const int rh = r - 192; const int gate = rh/256, c = rh%256;
      v = whh[(size_t)(gate*E_ + jj)*E_ + c];
    }
    s_we[idx] = v;
  }
  __syncthreads();

  const int j0l = 2*w, j1l = 2*w + 1;
  const int j0 = jjg*8 + j0l, j1 = j0 + 1;

  const float brz0 = bih[j0] + bhh[j0];
  const float brz1 = bih[j1] + bhh[j1];
  const float bz0  = bih[E_+j0] + bhh[E_+j0];
  const float bz1  = bih[E_+j1] + bhh[E_+j1];
  const float bni0 = bih[2*E_+j0], bni1 = bih[2*E_+j1];
  const float bnh0 = bhh[2*E_+j0], bnh1 = bhh[2*E_+j1];

  const float4* wr0x = (const float4*)(s_we + j0l*960);
  const float4* wz0x = (const float4*)(s_we + j0l*960 + 64);
  const float4* wn0x = (const float4*)(s_we + j0l*960 + 128);
  const float4* wr0h = (const float4*)(s_we + j0l*960 + 192);
  const float4* wz0h = (const float4*)(s_we + j0l*960 + 448);
  const float4* wn0h = (const float4*)(s_we + j0l*960 + 704);
  const float4* wr1x = (const float4*)(s_we + j1l*960);
  const float4* wz1x = (const float4*)(s_we + j1l*960 + 64);
  const float4* wn1x = (const float4*)(s_we + j1l*960 + 128);
  const float4* wr1h = (const float4*)(s_we + j1l*960 + 192);
  const float4* wz1h = (const float4*)(s_we + j1l*960 + 448);
  const float4* wn1h = (const float4*)(s_we + j1l*960 + 704);

  int alive = 1;
  int p = 0;
  for (int t = 0; t < T_; ++t) {
    const int tt = bwd ? (T_-1-t) : t;
    const float* xp = a.xT + (size_t)tt*(B_*DIN_) + (size_t)b*DIN_;
    const float* hp = hTc + (size_t)p*GEB + (size_t)b*E_;
    float ar0=0,az0=0,an0=0,ah0=0, ar1=0,az1=0,an1=0,ah1=0;
    for (int k4 = 0; k4 < 16; ++k4) {
      const float4 x4 = *(const float4*)(xp + 4*k4);
      float4 v;
      v = wr0x[k4]; ar0 += v.x*x4.x + v.y*x4.y + v.z*x4.z + v.w*x4.w;
      v = wz0x[k4]; az0 += v.x*x4.x + v.y*x4.y + v.z*x4.z + v.w*x4.w;
      v = wn0x[k4]; an0 += v.x*x4.x + v.y*x4.y + v.z*x4.z + v.w*x4.w;
      v = wr1x[k4]; ar1 += v.x*x4.x + v.y*x4.y + v.z*x4.z + v.w*x4.w;
      v = wz1x[k4]; az1 += v.x*x4.x + v.y*x4.y + v.z*x4.z + v.w*x4.w;
      v = wn1x[k4]; an1 += v.x*x4.x + v.y*x4.y + v.z*x4.z + v.w*x4.w;
    }
    for (int k4 = 0; k4 < 64; ++k4) {
      const float4 h4 = *(const float4*)(hp + 4*k4);
      float4 v;
      v = wr0h[k4]; ar0 += v.x*h4.x + v.y*h4.y + v.z*h4.z + v.w*h4.w;
      v = wz0h[k4]; az0 += v.x*h4.x + v.y*h4.y + v.z*h4.z + v.w*h4.w;
      v = wn0h[k4]; ah0 += v.x*h4.x + v.y*h4.y + v.z*h4.z + v.w*h4.w;
      v = wr1h[k4]; ar1 += v.x*h4.x + v.y*h4.y + v.z*h4.z + v.w*h4.w;
      v = wz1h[k4]; az1 += v.x*h4.x + v.y*h4.y + v.z*h4.z + v.w*h4.w;
      v = wn1h[k4]; ah1 += v.x*h4.x + v.y*h4.y + v.z*h4.z + v.w*h4.w;
    }
    const float hprev0 = hp[j0];
    const float hprev1 = hp[j1];
    const float r0 = sigm_(ar0 + brz0);
    const float z0 = sigm_(az0 + bz0);
    const float n0 = tanhf(an0 + bni0 + r0*(ah0 + bnh0));
    const float h0n = fminf((1.0f - z0)*n0 + z0*hprev0, CLIPV);
    const float r1 = sigm_(ar1 + brz1);
    const float z1 = sigm_(az1 + bz1);
    const float n1 = tanhf(an1 + bni1 + r1*(ah1 + bnh1));
    const float h1n = fminf((1.0f - z1)*n1 + z1*hprev1, CLIPV);
    float* hq = hTc + (size_t)(p^1)*GEB + (size_t)b*E_;
    hq[j0] = h0n;
    hq[j1] = h1n;
    if (st) {
      st[(size_t)tt*GEB + (size_t)j0*B_ + b] = __float2bfloat16(h0n);
      st[(size_t)tt*GEB + (size_t)j1*B_ + b] = __float2bfloat16(h1n);
    }
    slot_wait(slots, 64, myslot, t+1, t+1, &s_goE, alive);
    p ^= 1;
  }
}

// ------------------------- g0 sample ----------------------------------------

__global__ void k_g0(const float* __restrict__ hT, const float* __restrict__ g0mw,
                     const float* __restrict__ g0mb, const float* __restrict__ g0vw,
                     const float* __restrict__ g0vb, const float* __restrict__ eps_g0,
                     float* __restrict__ gT) {
  const int b = threadIdx.x & 127;
  const int half = threadIdx.x >> 7;
  const int kout = blockIdx.x*2 + half;
  const float* hf = hT + (size_t)b*E_;             // chain0 (egf), buffer 0
  const float* hb = hT + 4*GEB + (size_t)b*E_;     // chain2 (egb), buffer 0
  const float* mrow = g0mw + (size_t)kout*512;
  const float* vrow = g0vw + (size_t)kout*512;
  float dm = 0.0f, dv = 0.0f;
  for (int k = 0; k < E_; ++k) {
    const float hv = hf[k];
    dm += mrow[k]*hv; dv += vrow[k]*hv;
  }
  for (int k = 0; k < E_; ++k) {
    const float hv = hb[k];
    dm += mrow[256+k]*hv; dv += vrow[256+k]*hv;
  }
  const float lv = fmaxf(dv + g0vb[kout], LVMIN_);
  gT[(size_t)b*E_ + kout] = eps_g0[(size_t)b*E_ + kout]*expf(0.5f*lv) + dm + g0mb[kout];
}

// ------------------------- generator (3 roles) -------------------------------

struct GenAll {
  const float* M; const float* conwhh; const float* genwhh;
  const float* conbih; const float* conbhh; const float* Wfb;
  const float* genwih; const float* genbih; const float* genbhh;
  const float* umw; const float* umb; const float* uvw; const float* uvb;
  const float* epsT;          // [T][2][B]
  const float* conwih;        // [768][576]
  const __hip_bfloat16* efS;  // [T][E][B]
  const __hip_bfloat16* ebS;
  __hip_bfloat16* ge;         // ring [128][768][B]
  float* gT; float* cT;       // [2][B][E]
  const float* facw; const float* facb;
  const float* f1w; const float* f1b;
  const float* clw; const float* clb;
  float* out;                 // [B][T][DOUT]
  int* arr_main;              // 160 slots stride 16
  int* flags;                 // 128 slots stride 16
};

__global__ __launch_bounds__(256, 1) void k_generator(GenAll a) {
  __shared__ __align__(16) unsigned char s_raw[60416];
  const int lane = threadIdx.x & 63;
  const int w = threadIdx.x >> 6;

  if (blockIdx.x < 128) {
    // ======================= consumer =======================
    float* s_w   = (float*)s_raw;              // 4*2304 f32 = 36864 B
    float* s_uwT = (float*)(s_raw + 36864);    // [k][4]     = 4096 B
    float* s_up  = (float*)(s_raw + 40960);    // [4][256]   = 4096 B
    volatile int* s_go = (volatile int*)(s_raw + 45056);
    const int jjgq = blockIdx.x >> 1;
    const int bg = blockIdx.x & 1;
    const int b = bg*64 + lane;

    for (int idx = threadIdx.x; idx < 9216; idx += 256) {
      const int jl = idx / 2304, r = idx % 2304;
      const int jj = jjgq*4 + jl;
      const int sec = r / 768, rr = r % 768, gate = rr >> 8, c = rr & 255;
      const float* src = (sec == 0) ? a.M : (sec == 1 ? a.conwhh : a.genwhh);
      s_w[idx] = src[(size_t)(gate*E_ + jj)*E_ + c];
    }
    for (int idx = threadIdx.x; idx < 1024; idx += 256) {
      const int k = idx >> 2, q = idx & 3;
      s_uwT[idx] = (q < 2) ? a.umw[q*E_ + k] : a.uvw[(q-2)*E_ + k];
    }
    __syncthreads();

    const int j = jjgq*4 + w;
    const float* base = s_w + w*2304;
    const float4* Mr  = (const float4*)(base);
    const float4* Mz  = (const float4*)(base + 256);
    const float4* Mn  = (const float4*)(base + 512);
    const float4* Whr = (const float4*)(base + 768);
    const float4* Whz = (const float4*)(base + 1024);
    const float4* Whn = (const float4*)(base + 1280);
    const float4* Gwr = (const float4*)(base + 1536);
    const float4* Gwz = (const float4*)(base + 1792);
    const float4* Gwn = (const float4*)(base + 2048);

    const float brz_c = a.conbih[j] + a.conbhh[j] + a.Wfb[j];
    const float bz_c  = a.conbih[E_+j] + a.conbhh[E_+j] + a.Wfb[E_+j];
    const float bni_c = a.conbih[2*E_+j] + a.Wfb[2*E_+j];
    const float bnh_c = a.conbhh[2*E_+j];
    const float gur0 = a.genwih[j*2],        gur1 = a.genwih[j*2+1];
    const float guz0 = a.genwih[(E_+j)*2],   guz1 = a.genwih[(E_+j)*2+1];
    const float gun0 = a.genwih[(2*E_+j)*2], gun1 = a.genwih[(2*E_+j)*2+1];
    const float brz_g = a.genbih[j] + a.genbhh[j];
    const float bz_g  = a.genbih[E_+j] + a.genbhh[E_+j];
    const float bni_g = a.genbih[2*E_+j];
    const float bnh_g = a.genbhh[2*E_+j];
    const float umb0 = a.umb[0], umb1 = a.umb[1];
    const float uvb0 = a.uvb[0], uvb1 = a.uvb[1];

    int* myslot = a.arr_main + blockIdx.x*16;
    int alive = 1;
    for (int t = 0; t < T_; ++t) {
      const float* gpb = a.gT + (size_t)(t&1)*GEB + (size_t)b*E_;
      const float* cpb = a.cT + (size_t)(t&1)*GEB + (size_t)b*E_;
      float ar=0,az=0,an=0,ah=0,gr=0,gz=0,gh=0;
      for (int k4 = 0; k4 < 64; ++k4) {
        const float4 g4 = *(const float4*)(gpb + 4*k4);
        const float4 c4 = *(const float4*)(cpb + 4*k4);
        float4 v;
        v = Mr[k4];  ar += v.x*g4.x + v.y*g4.y + v.z*g4.z + v.w*g4.w;
        v = Mz[k4];  az += v.x*g4.x + v.y*g4.y + v.z*g4.z + v.w*g4.w;
        v = Mn[k4];  an += v.x*g4.x + v.y*g4.y + v.z*g4.z + v.w*g4.w;
        v = Gwr[k4]; gr += v.x*g4.x + v.y*g4.y + v.z*g4.z + v.w*g4.w;
        v = Gwz[k4]; gz += v.x*g4.x + v.y*g4.y + v.z*g4.z + v.w*g4.w;
        v = Gwn[k4]; gh += v.x*g4.x + v.y*g4.y + v.z*g4.z + v.w*g4.w;
        v = Whr[k4]; ar += v.x*c4.x + v.y*c4.y + v.z*c4.z + v.w*c4.w;
        v = Whz[k4]; az += v.x*c4.x + v.y*c4.y + v.z*c4.z + v.w*c4.w;
        v = Whn[k4]; ah += v.x*c4.x + v.y*c4.y + v.z*c4.z + v.w*c4.w;
      }
      // wait for producers of ge[t], then add its 3 contributions
      flag_wait(a.flags + (t & 127)*16, 48*((t >> 7) + 1), s_go, alive);
      const ushort_t* gep = (const ushort_t*)a.ge + (size_t)(t & 127)*(768*B_);
      ar += bfu_(gep[(size_t)j*B_ + b]);
      az += bfu_(gep[(size_t)(E_+j)*B_ + b]);
      an += bfu_(gep[(size_t)(2*E_+j)*B_ + b]);
      const float cprev = cpb[j];
      const float r = sigm_(ar + brz_c);
      const float z = sigm_(az + bz_c);
      const float n = tanhf(an + bni_c + r*(ah + bnh_c));
      const float cn = fminf((1.0f - z)*n + z*cprev, CLIPV);
      a.cT[(size_t)((t+1)&1)*GEB + (size_t)b*E_ + j] = cn;
      slot_wait(a.arr_main, 160, myslot, 2*t+1, 2*t+1, s_go, alive);

      // ---- u partials over this wave's k-quarter of fresh c ----
      const float* cq = a.cT + (size_t)((t+1)&1)*GEB + (size_t)b*E_ + w*64;
      float p0=0,p1=0,p2=0,p3=0;
      for (int kk = 0; kk < 16; ++kk) {
        const float4 c4 = *(const float4*)(cq + 4*kk);
        const float4 w0 = *(const float4*)(s_uwT + (w*64 + 4*kk + 0)*4);
        const float4 w1 = *(const float4*)(s_uwT + (w*64 + 4*kk + 1)*4);
        const float4 w2 = *(const float4*)(s_uwT + (w*64 + 4*kk + 2)*4);
        const float4 w3 = *(const float4*)(s_uwT + (w*64 + 4*kk + 3)*4);
        p0 += w0.x*c4.x + w1.x*c4.y + w2.x*c4.z + w3.x*c4.w;
        p1 += w0.y*c4.x + w1.y*c4.y + w2.y*c4.z + w3.y*c4.w;
        p2 += w0.z*c4.x + w1.z*c4.y + w2.z*c4.z + w3.z*c4.w;
        p3 += w0.w*c4.x + w1.w*c4.y + w2.w*c4.z + w3.w*c4.w;
      }
      s_up[0*256 + threadIdx.x] = p0;
      s_up[1*256 + threadIdx.x] = p1;
      s_up[2*256 + threadIdx.x] = p2;
      s_up[3*256 + threadIdx.x] = p3;
      __syncthreads();
      const float m0 = s_up[lane] + s_up[64+lane] + s_up[128+lane] + s_up[192+lane] + umb0;
      const float m1 = s_up[256+lane] + s_up[320+lane] + s_up[384+lane] + s_up[448+lane] + umb1;
      const float lv0 = fmaxf(s_up[512+lane] + s_up[576+lane] + s_up[640+lane] + s_up[704+lane] + uvb0, LVMIN_);
      const float lv1 = fmaxf(s_up[768+lane] + s_up[832+lane] + s_up[896+lane] + s_up[960+lane] + uvb1, LVMIN_);
      const float eps0 = a.epsT[(size_t)t*256 + b];
      const float eps1 = a.epsT[(size_t)t*256 + 128 + b];
      const float u0 = eps0*expf(0.5f*lv0) + m0;
      const float u1 = eps1*expf(0.5f*lv1) + m1;

      const float rg = sigm_(gr + gur0*u0 + gur1*u1 + brz_g);
      const float zg = sigm_(gz + guz0*u0 + guz1*u1 + bz_g);
      const float ng = tanhf(gun0*u0 + gun1*u1 + bni_g + rg*(gh + bnh_g));
      const float gprev = gpb[j];
      const float gn = fminf((1.0f - zg)*ng + zg*gprev, CLIPV);
      a.gT[(size_t)((t+1)&1)*GEB + (size_t)b*E_ + j] = gn;
      slot_wait(a.arr_main, 160, myslot, 2*t+2, 2*t+2, s_go, alive);
    }
  } else if (blockIdx.x < 224) {
    // ======================= producer =======================
    float* s_wp = (float*)s_raw;                   // [512][16] f32 = 32768 B
    volatile int* s_go = (volatile int*)(s_raw + 32768);
    const int pid = blockIdx.x - 128;
    const int tile = pid % 48, phase = pid / 48;
    const int r0 = tile*16;
    for (int idx = threadIdx.x; idx < 8192; idx += 256) {
      const int k = idx >> 4, rl = idx & 15;
      s_wp[idx] = a.conwih[(size_t)(r0 + rl)*576 + k];
    }
    __syncthreads();
    const int half = w & 1, rq = w >> 1;
    const int b = half*64 + lane, rl0 = rq*8;
    int alive = 1;
    for (int t = phase; t < T_; t += 2) {
      if (t >= 128)   // don't clobber ring slot until consumers are past t-128
        slot_wait(a.arr_main, 160, nullptr, 0, 2*(t-126)+1, s_go, alive);
      float acc[8] = {0,0,0,0,0,0,0,0};
      const ushort_t* efp = (const ushort_t*)a.efS + (size_t)t*GEB + b;
      const ushort_t* ebp = (const ushort_t*)a.ebS + (size_t)t*GEB + b;
      for (int k = 0; k < 256; ++k) {
        const float ev = bfu_(efp[(size_t)k*B_]);
        const float4 w0 = *(const float4*)(s_wp + k*16 + rl0);
        const float4 w1 = *(const float4*)(s_wp + k*16 + rl0 + 4);
        acc[0]+=w0.x*ev; acc[1]+=w0.y*ev; acc[2]+=w0.z*ev; acc[3]+=w0.w*ev;
        acc[4]+=w1.x*ev; acc[5]+=w1.y*ev; acc[6]+=w1.z*ev; acc[7]+=w1.w*ev;
      }
      for (int k = 0; k < 256; ++k) {
        const float ev = bfu_(ebp[(size_t)k*B_]);
        const float4 w0 = *(const float4*)(s_wp + (256+k)*16 + rl0);
        const float4 w1 = *(const float4*)(s_wp + (256+k)*16 + rl0 + 4);
        acc[0]+=w0.x*ev; acc[1]+=w0.y*ev; acc[2]+=w0.z*ev; acc[3]+=w0.w*ev;
        acc[4]+=w1.x*ev; acc[5]+=w1.y*ev; acc[6]+=w1.z*ev; acc[7]+=w1.w*ev;
      }
      __hip_bfloat16* gesl = a.ge + (size_t)(t & 127)*(768*B_) + (size_t)(r0 + rl0)*B_ + b;
      for (int i = 0; i < 8; ++i) gesl[(size_t)i*B_] = __float2bfloat16(acc[i]);
      __syncthreads();
      if (threadIdx.x == 0)
        __hip_atomic_fetch_add(a.flags + (t & 127)*16, 1, __ATOMIC_RELEASE, __HIP_MEMORY_SCOPE_AGENT);
    }
  } else {
    // ======================= output MLP =======================
    __hip_bfloat16* s_fw  = (__hip_bfloat16*)s_raw;              // [256][64] 32768 B
    __hip_bfloat16* s_f1T = (__hip_bfloat16*)(s_raw + 32768);    // [64][80] 10240 B
    __hip_bfloat16* s_clT = (__hip_bfloat16*)(s_raw + 43008);    // [80][64] 10240 B
    float* s_g  = (float*)(s_raw + 53248);                       // [4][256] 4096 B
    float* s_f  = (float*)(s_raw + 57344);                       // [4][64]  1024 B
    float* s_h1 = (float*)(s_raw + 58368);                       // [4][80]  1280 B
    volatile int* s_go = (volatile int*)(s_raw + 59648);
    for (int idx = threadIdx.x; idx < 16384; idx += 256) {
      const int k = idx >> 6, fd = idx & 63;
      s_fw[idx] = __float2bfloat16(a.facw[(size_t)fd*E_ + k]);
    }
    for (int idx = threadIdx.x; idx < 5120; idx += 256) {
      const int kf = idx / H1_, hd = idx % H1_;
      s_f1T[idx] = __float2bfloat16(a.f1w[(size_t)hd*64 + kf]);
    }
    for (int idx = threadIdx.x; idx < 5120; idx += 256) {
      const int kh = idx >> 6, od = idx & 63;
      s_clT[idx] = __float2bfloat16(a.clw[(size_t)od*H1_ + kh]);
    }
    __syncthreads();
    const int oid = blockIdx.x - 224;
    const int b = oid*4 + w;
    const float facb_l = a.facb[lane];
    const float f1b_a  = a.f1b[lane];
    const float f1b_b  = (lane < 16) ? a.f1b[64 + lane] : 0.0f;
    const float clb_l  = a.clb[lane];
    int* myslot = a.arr_main + (128 + oid)*16;
    int alive = 1;
    for (int t = 0; t <= T_; ++t) {
      const int tt = t - 1;
      if (tt >= 0) {
        const float* gq = a.gT + (size_t)((tt+1)&1)*GEB + (size_t)b*E_;
        *(float4*)(s_g + w*256 + lane*4) = *(const float4*)(gq + lane*4);
        float f = facb_l;
        for (int k = 0; k < 256; ++k)
          f += __bfloat162float(s_fw[k*64 + lane]) * s_g[w*256 + k];
        s_f[w*64 + lane] = f;
        float h1a = f1b_a, h1b = f1b_b;
        for (int kf = 0; kf < 64; ++kf) {
          const float fv = s_f[w*64 + kf];
          h1a += __bfloat162float(s_f1T[kf*H1_ + lane]) * fv;
          if (lane < 16) h1b += __bfloat162float(s_f1T[kf*H1_ + 64 + lane]) * fv;
        }
        s_h1[w*H1_ + lane] = fmaxf(h1a, 0.0f);
        if (lane < 16) s_h1[w*H1_ + 64 + lane] = fmaxf(h1b, 0.0f);
        float o = clb_l;
        for (int kh = 0; kh < H1_; ++kh)
          o += __bfloat162float(s_clT[kh*64 + lane]) * s_h1[w*H1_ + kh];
        a.out[((size_t)b*T_ + tt)*DOUT_ + lane] = o;
      }
      if (t == T_) break;
      slot_wait(a.arr_main, 160, myslot, 2*t+1, 2*t+1, s_go, alive);
      slot_wait(a.arr_main, 160, myslot, 2*t+2, 2*t+2, s_go, alive);
    }
  }
}

// ------------------------- host launcher ------------------------------------

extern "C" void kernel_launch(void* const* d_in, const int* in_sizes, int n_in,
                              void* d_out, int out_size, void* d_ws, size_t ws_size,
                              hipStream_t stream) {
  const float* x      = (const float*)d_in[0];
  const float* eps_g0 = (const float*)d_in[1];
  const float* eps_u  = (const float*)d_in[2];
  const float* egf_wih = (const float*)d_in[3],  *egf_whh = (const float*)d_in[4];
  const float* egf_bih = (const float*)d_in[5],  *egf_bhh = (const float*)d_in[6];
  const float* egb_wih = (const float*)d_in[7],  *egb_whh = (const float*)d_in[8];
  const float* egb_bih = (const float*)d_in[9],  *egb_bhh = (const float*)d_in[10];
  const float* ecf_wih = (const float*)d_in[11], *ecf_whh = (const float*)d_in[12];
  const float* ecf_bih = (const float*)d_in[13], *ecf_bhh = (const float*)d_in[14];
  const float* ecb_wih = (const float*)d_in[15], *ecb_whh = (const float*)d_in[16];
  const float* ecb_bih = (const float*)d_in[17], *ecb_bhh = (const float*)d_in[18];
  const float* con_wih = (const float*)d_in[19], *con_whh = (const float*)d_in[20];
  const float* con_bih = (const float*)d_in[21], *con_bhh = (const float*)d_in[22];
  const float* gen_wih = (const float*)d_in[23], *gen_whh = (const float*)d_in[24];
  const float* gen_bih = (const float*)d_in[25], *gen_bhh = (const float*)d_in[26];
  const float* g0m_w = (const float*)d_in[27], *g0m_b = (const float*)d_in[28];
  const float* g0v_w = (const float*)d_in[29], *g0v_b = (const float*)d_in[30];
  const float* um_w = (const float*)d_in[31], *um_b = (const float*)d_in[32];
  const float* uv_w = (const float*)d_in[33], *uv_b = (const float*)d_in[34];
  const float* fac_w = (const float*)d_in[35], *fac_b = (const float*)d_in[36];
  const float* f1_w = (const float*)d_in[37], *f1_b = (const float*)d_in[38];
  const float* cl_w = (const float*)d_in[39], *cl_b = (const float*)d_in[40];
  float* out = (float*)d_out;
  (void)ws_size; (void)in_sizes; (void)n_in; (void)out_size;

  // Workspace layout — total 167,262,208 B <= proven 167,297,024 B (round 0).
  // ge ring (25,165,824 B) aliases xT (dead after encoder).
  char* ws = (char*)d_ws;
  const size_t o_xT   = 0;             // f32 [T][B][DIN]        32,768,000
  const size_t o_ge   = 0;             // bf16 [128][768][B]     25,165,824 (alias)
  const size_t o_efS  = 32768000ul;    // bf16 [T][E][B]         65,536,000
  const size_t o_ebS  = 98304000ul;    //                        65,536,000
  const size_t o_epsT = 163840000ul;   // f32 [T][2][B]           1,024,000
  const size_t o_M    = 164864000ul;   // f32 [768][E]              786,432
  const size_t o_Wfb  = 165650432ul;   // f32 [768]                   4,096
  const size_t o_hT   = 165654528ul;   // f32 [4][2][B][E]        1,048,576
  const size_t o_gT   = 166703104ul;   // f32 [2][B][E]             262,144
  const size_t o_cT   = 166965248ul;   //                           262,144
  const size_t o_ctl  = 167227392ul;   // int slots                  34,816
  const size_t o_end  = 167262208ul;

  float* xT = (float*)(ws + o_xT);
  __hip_bfloat16* ge = (__hip_bfloat16*)(ws + o_ge);
  __hip_bfloat16* efS = (__hip_bfloat16*)(ws + o_efS);
  __hip_bfloat16* ebS = (__hip_bfloat16*)(ws + o_ebS);
  float* epsT = (float*)(ws + o_epsT);
  float* M = (float*)(ws + o_M);
  float* Wfb = (float*)(ws + o_Wfb);
  float* hT = (float*)(ws + o_hT);
  float* gT = (float*)(ws + o_gT);
  float* cT = (float*)(ws + o_cT);
  int* ctl = (int*)(ws + o_ctl);
  int* arr_main = ctl;           // 160 slots * 16 ints
  int* flags    = ctl + 2560;    // 128 slots * 16 ints
  int* arr_enc  = ctl + 4608;    // 4*64 slots * 16 ints

  // ROUND-3 FIX: zero the ENTIRE state+control region (round 2 only zeroed
  // 4,096 B of ctl -> flags stayed 0xAA-poisoned -> every flag_wait timed out
  // at the 200k guard (~40-90 ms) and the kernel free-ran unsynchronized).
  hipMemsetAsync(ws + o_hT, 0, o_end - o_hT, stream);

  k_transpose_x<<<T_, 256, 0, stream>>>(x, xT);
  k_transpose_eps<<<T_, 256, 0, stream>>>(eps_u, epsT);
  k_composite<<<768, 256, 0, stream>>>(con_wih, fac_w, fac_b, M, Wfb);

  EncArgs ea;
  ea.xT = xT;
  ea.wih[0] = egf_wih; ea.whh[0] = egf_whh; ea.bih[0] = egf_bih; ea.bhh[0] = egf_bhh;
  ea.wih[1] = ecf_wih; ea.whh[1] = ecf_whh; ea.bih[1] = ecf_bih; ea.bhh[1] = ecf_bhh;
  ea.wih[2] = egb_wih; ea.whh[2] = egb_whh; ea.bih[2] = egb_bih; ea.bhh[2] = egb_bhh;
  ea.wih[3] = ecb_wih; ea.whh[3] = ecb_whh; ea.bih[3] = ecb_bih; ea.bhh[3] = ecb_bhh;
  ea.hT = hT; ea.efS = efS; ea.ebS = ebS; ea.arr = arr_enc;
  k_encoder<<<256, 256, 0, stream>>>(ea);

  k_g0<<<128, 256, 0, stream>>>(hT, g0m_w, g0m_b, g0v_w, g0v_b, eps_g0, gT);

  GenAll ga;
  ga.M = M; ga.conwhh = con_whh; ga.genwhh = gen_whh;
  ga.conbih = con_bih; ga.conbhh = con_bhh; ga.Wfb = Wfb;
  ga.genwih = gen_wih; ga.genbih = gen_bih; ga.genbhh = gen_bhh;
  ga.umw = um_w; ga.umb = um_b; ga.uvw = uv_w; ga.uvb = uv_b;
  ga.epsT = epsT; ga.conwih = con_wih;
  ga.efS = efS; ga.ebS = ebS; ga.ge = ge;
  ga.gT = gT; ga.cT = cT;
  ga.facw = fac_w; ga.facb = fac_b;
  ga.f1w = f1_w; ga.f1b = f1_b; ga.clw = cl_w; ga.clb = cl_b;
  ga.out = out;
  ga.arr_main = arr_main; ga.flags = flags;
  k_generator<<<256, 256, 0, stream>>>(ga);
}

// Round 5
// 57518.903 us; speedup vs baseline: 1.6130x; 1.3260x over previous
//
#include <hip/hip_runtime.h>
#include <hip/hip_bf16.h>
#include <stdint.h>
#include <stddef.h>

// ---------------------------------------------------------------------------
// LFADS forward on MI355X — round 4: FENCE-FREE cross-WG coherence.
// Rounds 0-3 all paid ~35-55us/step in agent-scope release/acquire ops
// (buffer_wbl2 + L2 invalidate per step per WG). This round:
//  - all cross-WG state via relaxed agent atomics (sc0|sc1 bypass, no fences)
//  - data->flag ordering via explicit `s_waitcnt vmcnt(0)`
//  - weights read from global, L1/L2-cached (nothing invalidates them now)
//  - activations back to coalesced [k][b]; (g,c) packed into one u64 load
// ---------------------------------------------------------------------------

#define B_    128
#define T_    1000
#define DIN_  64
#define E_    256
#define F_    64
#define H1_   80
#define DOUT_ 64
#define GEB   (E_*B_)
#define CLIPV 5.0f
#define LVMIN_ (-9.210340371976182f)

typedef unsigned short ushort_t;
typedef unsigned int uint_t;
typedef unsigned long long ull_t;

__device__ __forceinline__ float sigm_(float x) { return 1.0f/(1.0f + expf(-x)); }
__device__ __forceinline__ float bfu_(ushort_t u) { return __uint_as_float(((unsigned)u) << 16); }
__device__ __forceinline__ ushort_t bfbits_(float f) {
  __hip_bfloat16 h = __float2bfloat16(f);
  return *reinterpret_cast<ushort_t*>(&h);
}
__device__ __forceinline__ void vm_drain() { asm volatile("s_waitcnt vmcnt(0)" ::: "memory"); }

__device__ __forceinline__ float ldc_f32(const float* p) {
  return __hip_atomic_load(p, __ATOMIC_RELAXED, __HIP_MEMORY_SCOPE_AGENT);
}
__device__ __forceinline__ void stc_f32(float* p, float v) {
  __hip_atomic_store(p, v, __ATOMIC_RELAXED, __HIP_MEMORY_SCOPE_AGENT);
}
__device__ __forceinline__ uint_t ldc_u32(const uint_t* p) {
  return __hip_atomic_load(p, __ATOMIC_RELAXED, __HIP_MEMORY_SCOPE_AGENT);
}
__device__ __forceinline__ void stc_u32(uint_t* p, uint_t v) {
  __hip_atomic_store(p, v, __ATOMIC_RELAXED, __HIP_MEMORY_SCOPE_AGENT);
}
__device__ __forceinline__ ull_t ldc_u64(const ull_t* p) {
  return __hip_atomic_load(p, __ATOMIC_RELAXED, __HIP_MEMORY_SCOPE_AGENT);
}

// Slot barrier: drain own stores, post (relaxed), poll min over n slots.
// NO fences — all shared data moves via sc-bypass atomics.
__device__ __forceinline__ void slot_wait(int* slots, int n, int* mine, int val,
                                          int target, volatile int* s_go, int& alive) {
  if (!alive) return;
  const int lane = threadIdx.x & 63;
  const int w = threadIdx.x >> 6;
  vm_drain();              // every wave: its stores reached coherence point
  __syncthreads();         // all waves arrived
  if (mine != nullptr && threadIdx.x == 0)
    __hip_atomic_store(mine, val, __ATOMIC_RELAXED, __HIP_MEMORY_SCOPE_AGENT);
  int guard = 0;
  for (;;) {
    if (w == 0) {
      int mn = 0x7fffffff;
      for (int i = lane; i < n; i += 64) {
        const int v = __hip_atomic_load(&slots[i*16], __ATOMIC_RELAXED, __HIP_MEMORY_SCOPE_AGENT);
        mn = (v < mn) ? v : mn;
      }
      const unsigned long long ok = __ballot(mn >= target);
      if (lane == 0) *s_go = (ok == ~0ull) ? 1 : 0;
    }
    __syncthreads();
    const int go = *s_go;
    __syncthreads();
    if (go) break;
    if (++guard > 200000) { alive = 0; break; }
    __builtin_amdgcn_s_sleep(1);
  }
}

__device__ __forceinline__ void flag_wait(int* flag, int target,
                                          volatile int* s_go, int& alive) {
  if (!alive) return;
  const int w = threadIdx.x >> 6;
  __syncthreads();
  int guard = 0;
  for (;;) {
    if (w == 0) {
      const int v = __hip_atomic_load(flag, __ATOMIC_RELAXED, __HIP_MEMORY_SCOPE_AGENT);
      if ((threadIdx.x & 63) == 0) *s_go = (v >= target) ? 1 : 0;
    }
    __syncthreads();
    const int go = *s_go;
    __syncthreads();
    if (go) break;
    if (++guard > 200000) { alive = 0; break; }
    __builtin_amdgcn_s_sleep(1);
  }
}

// ------------------------- prep kernels ------------------------------------

// x[B][T][DIN] -> xT[T][DIN][B]
__global__ void k_transpose_x(const float* __restrict__ x, float* __restrict__ xT) {
  __shared__ float tile[64][65];
  const int t = blockIdx.x, bh = blockIdx.y;
  const int lane = threadIdx.x & 63, w = threadIdx.x >> 6;
  for (int i = 0; i < 16; ++i) {
    const int bl = w*16 + i;
    tile[bl][lane] = x[(size_t)(bh*64 + bl)*(T_*DIN_) + (size_t)t*DIN_ + lane];
  }
  __syncthreads();
  for (int i = 0; i < 16; ++i) {
    const int k = w*16 + i;
    xT[(size_t)t*(DIN_*B_) + (size_t)k*B_ + bh*64 + lane] = tile[lane][k];
  }
}

// eps_u[B][T][2] -> epsT[T][2][B]
__global__ void k_transpose_eps(const float* __restrict__ eps_u, float* __restrict__ epsT) {
  const int t = blockIdx.x;
  const int o = threadIdx.x >> 7, b = threadIdx.x & 127;
  epsT[(size_t)t*2*B_ + o*B_ + b] = eps_u[(size_t)b*(T_*2) + t*2 + o];
}

// M[768][E] = con_wih[:,512:576] @ fac_w ; Wfb[768] = con_wih[:,512:576] @ fac_b
__global__ void k_composite(const float* __restrict__ conwih, const float* __restrict__ facw,
                            const float* __restrict__ facb, float* __restrict__ M,
                            float* __restrict__ Wfb) {
  const int idx = blockIdx.x*256 + threadIdx.x;
  const int j = idx >> 8, k = idx & 255;
  float acc = 0.0f;
  for (int ff = 0; ff < F_; ++ff)
    acc += conwih[(size_t)j*576 + 512 + ff] * facw[(size_t)ff*E_ + k];
  M[(size_t)j*E_ + k] = acc;
  if (k == 0) {
    float s = 0.0f;
    for (int ff = 0; ff < F_; ++ff) s += conwih[(size_t)j*576 + 512 + ff] * facb[ff];
    Wfb[j] = s;
  }
}

// ------------------------- encoder -----------------------------------------

struct EncArgs {
  const float* xT;             // [T][DIN][B]
  const float* wih[4];
  const float* whh[4];
  const float* bih[4];
  const float* bhh[4];
  float* hT;                   // [4][2][E][B]
  __hip_bfloat16* efS;         // [T][E][B]
  __hip_bfloat16* ebS;
  int* arr;                    // 4*64 slots, stride 16
};

__global__ __launch_bounds__(256, 1) void k_encoder(EncArgs a) {
  __shared__ int s_goE;
  const int chain = blockIdx.x >> 6;
  const int rnk   = blockIdx.x & 63;
  const int jjg   = rnk >> 1;
  const int bg    = rnk & 1;
  const int lane  = threadIdx.x & 63;
  const int w     = threadIdx.x >> 6;
  const int b     = bg*64 + lane;

  const float* wih = a.wih[chain];
  const float* whh = a.whh[chain];
  const float* bih = a.bih[chain];
  const float* bhh = a.bhh[chain];
  float* hTc = a.hT + (size_t)chain*2*GEB;
  int* slots = a.arr + chain*1024;
  int* myslot = slots + rnk*16;
  const bool bwd = (chain >= 2);
  __hip_bfloat16* st = (chain == 1) ? a.efS : (chain == 3 ? a.ebS : nullptr);

  int j0 = jjg*8 + 2*w;
  j0 = __builtin_amdgcn_readfirstlane(j0);
  const int j1 = j0 + 1;

  const float brz0 = bih[j0] + bhh[j0];
  const float brz1 = bih[j1] + bhh[j1];
  const float bz0  = bih[E_+j0] + bhh[E_+j0];
  const float bz1  = bih[E_+j1] + bhh[E_+j1];
  const float bni0 = bih[2*E_+j0], bni1 = bih[2*E_+j1];
  const float bnh0 = bhh[2*E_+j0], bnh1 = bhh[2*E_+j1];

  // uniform weight row pointers (global; stays L1/L2-cached — no fences now)
  const float4* wr0x = (const float4*)(wih + (size_t)j0*DIN_);
  const float4* wz0x = (const float4*)(wih + (size_t)(E_+j0)*DIN_);
  const float4* wn0x = (const float4*)(wih + (size_t)(2*E_+j0)*DIN_);
  const float4* wr1x = (const float4*)(wih + (size_t)j1*DIN_);
  const float4* wz1x = (const float4*)(wih + (size_t)(E_+j1)*DIN_);
  const float4* wn1x = (const float4*)(wih + (size_t)(2*E_+j1)*DIN_);
  const float4* wr0h = (const float4*)(whh + (size_t)j0*E_);
  const float4* wz0h = (const float4*)(whh + (size_t)(E_+j0)*E_);
  const float4* wn0h = (const float4*)(whh + (size_t)(2*E_+j0)*E_);
  const float4* wr1h = (const float4*)(whh + (size_t)j1*E_);
  const float4* wz1h = (const float4*)(whh + (size_t)(E_+j1)*E_);
  const float4* wn1h = (const float4*)(whh + (size_t)(2*E_+j1)*E_);

  int alive = 1;
  int p = 0;
  for (int t = 0; t < T_; ++t) {
    const int tt = bwd ? (T_-1-t) : t;
    const float* xp = a.xT + (size_t)tt*DIN_*B_ + b;
    const float* hp = hTc + (size_t)p*GEB + b;
    float ar0=0,az0=0,an0=0,ah0=0, ar1=0,az1=0,an1=0,ah1=0;
    for (int k4 = 0; k4 < 16; ++k4) {
      const float x0 = xp[(4*k4+0)*B_], x1 = xp[(4*k4+1)*B_];
      const float x2 = xp[(4*k4+2)*B_], x3 = xp[(4*k4+3)*B_];
      float4 v;
      v = wr0x[k4]; ar0 += v.x*x0 + v.y*x1 + v.z*x2 + v.w*x3;
      v = wz0x[k4]; az0 += v.x*x0 + v.y*x1 + v.z*x2 + v.w*x3;
      v = wn0x[k4]; an0 += v.x*x0 + v.y*x1 + v.z*x2 + v.w*x3;
      v = wr1x[k4]; ar1 += v.x*x0 + v.y*x1 + v.z*x2 + v.w*x3;
      v = wz1x[k4]; az1 += v.x*x0 + v.y*x1 + v.z*x2 + v.w*x3;
      v = wn1x[k4]; an1 += v.x*x0 + v.y*x1 + v.z*x2 + v.w*x3;
    }
    for (int k4 = 0; k4 < 64; ++k4) {
      const float h0 = ldc_f32(hp + (4*k4+0)*B_);
      const float h1 = ldc_f32(hp + (4*k4+1)*B_);
      const float h2 = ldc_f32(hp + (4*k4+2)*B_);
      const float h3 = ldc_f32(hp + (4*k4+3)*B_);
      float4 v;
      v = wr0h[k4]; ar0 += v.x*h0 + v.y*h1 + v.z*h2 + v.w*h3;
      v = wz0h[k4]; az0 += v.x*h0 + v.y*h1 + v.z*h2 + v.w*h3;
      v = wn0h[k4]; ah0 += v.x*h0 + v.y*h1 + v.z*h2 + v.w*h3;
      v = wr1h[k4]; ar1 += v.x*h0 + v.y*h1 + v.z*h2 + v.w*h3;
      v = wz1h[k4]; az1 += v.x*h0 + v.y*h1 + v.z*h2 + v.w*h3;
      v = wn1h[k4]; ah1 += v.x*h0 + v.y*h1 + v.z*h2 + v.w*h3;
    }
    const float hprev0 = ldc_f32(hp + j0*B_);
    const float hprev1 = ldc_f32(hp + j1*B_);
    const float r0 = sigm_(ar0 + brz0);
    const float z0 = sigm_(az0 + bz0);
    const float n0 = tanhf(an0 + bni0 + r0*(ah0 + bnh0));
    const float h0n = fminf((1.0f - z0)*n0 + z0*hprev0, CLIPV);
    const float r1 = sigm_(ar1 + brz1);
    const float z1 = sigm_(az1 + bz1);
    const float n1 = tanhf(an1 + bni1 + r1*(ah1 + bnh1));
    const float h1n = fminf((1.0f - z1)*n1 + z1*hprev1, CLIPV);
    float* hq = hTc + (size_t)(p^1)*GEB;
    stc_f32(hq + j0*B_ + b, h0n);
    stc_f32(hq + j1*B_ + b, h1n);
    if (st) {   // archives are cross-kernel only: plain stores are fine
      st[(size_t)tt*GEB + (size_t)j0*B_ + b] = __float2bfloat16(h0n);
      st[(size_t)tt*GEB + (size_t)j1*B_ + b] = __float2bfloat16(h1n);
    }
    slot_wait(slots, 64, myslot, t+1, t+1, &s_goE, alive);
    p ^= 1;
  }
}

// ------------------------- g0 sample ----------------------------------------
// Writes g0 into packed PP[0][k][b].x (c stays 0 from memset).

__global__ void k_g0(const float* __restrict__ hT, const float* __restrict__ g0mw,
                     const float* __restrict__ g0mb, const float* __restrict__ g0vw,
                     const float* __restrict__ g0vb, const float* __restrict__ eps_g0,
                     float* __restrict__ ppx) {
  const int b = threadIdx.x & 127;
  const int half = threadIdx.x >> 7;
  const int kout = blockIdx.x*2 + half;
  const float* hf = hT;                 // chain0 (egf), buffer 0
  const float* hb = hT + 4*GEB;         // chain2 (egb), buffer 0
  const float* mrow = g0mw + (size_t)kout*512;
  const float* vrow = g0vw + (size_t)kout*512;
  float dm = 0.0f, dv = 0.0f;
  for (int k = 0; k < E_; ++k) {
    const float hv = hf[k*B_ + b];
    dm += mrow[k]*hv; dv += vrow[k]*hv;
  }
  for (int k = 0; k < E_; ++k) {
    const float hv = hb[k*B_ + b];
    dm += mrow[256+k]*hv; dv += vrow[256+k]*hv;
  }
  const float lv = fmaxf(dv + g0vb[kout], LVMIN_);
  const float g = eps_g0[(size_t)b*E_ + kout]*expf(0.5f*lv) + dm + g0mb[kout];
  ppx[((size_t)kout*B_ + b)*2] = g;     // .x of packed (g,c)
}

// ------------------------- generator (3 roles) -------------------------------

struct GenAll {
  const float* M; const float* conwhh; const float* genwhh;
  const float* conbih; const float* conbhh; const float* Wfb;
  const float* genwih; const float* genbih; const float* genbhh;
  const float* umw; const float* umb; const float* uvw; const float* uvb;
  const float* epsT;          // [T][2][B]
  const float* conwih;        // [768][576]
  const __hip_bfloat16* efS;  // [T][E][B]
  const __hip_bfloat16* ebS;
  uint_t* ge;                 // ring [128][768][B] bf16, u32 = 2 packed b's
  ull_t* PP;                  // [2][E][B] packed (g,c) f32 pairs
  const float* facw; const float* facb;
  const float* f1w; const float* f1b;
  const float* clw; const float* clb;
  float* out;                 // [B][T][DOUT]
  int* arr_main;              // 160 slots stride 16
  int* flags;                 // 128 slots stride 16
};

__global__ __launch_bounds__(256, 1) void k_generator(GenAll a) {
  __shared__ __align__(16) unsigned char s_raw[60416];
  const int lane = threadIdx.x & 63;
  const int w = threadIdx.x >> 6;

  if (blockIdx.x < 128) {
    // ======================= consumer =======================
    float* s_up = (float*)s_raw;                       // [4][256] 4096 B
    volatile int* s_go = (volatile int*)(s_raw + 4096);
    const int jjgq = blockIdx.x >> 1;
    const int bg = blockIdx.x & 1;
    const int b = bg*64 + lane;
    int j = jjgq*4 + w;
    j = __builtin_amdgcn_readfirstlane(j);

    const float4* Mr  = (const float4*)(a.M + (size_t)j*E_);
    const float4* Mz  = (const float4*)(a.M + (size_t)(E_+j)*E_);
    const float4* Mn  = (const float4*)(a.M + (size_t)(2*E_+j)*E_);
    const float4* Whr = (const float4*)(a.conwhh + (size_t)j*E_);
    const float4* Whz = (const float4*)(a.conwhh + (size_t)(E_+j)*E_);
    const float4* Whn = (const float4*)(a.conwhh + (size_t)(2*E_+j)*E_);
    const float4* Gwr = (const float4*)(a.genwhh + (size_t)j*E_);
    const float4* Gwz = (const float4*)(a.genwhh + (size_t)(E_+j)*E_);
    const float4* Gwn = (const float4*)(a.genwhh + (size_t)(2*E_+j)*E_);
    const float* uw0 = a.umw;            // row 0
    const float* uw1 = a.umw + E_;       // row 1
    const float* uw2 = a.uvw;            // row 0
    const float* uw3 = a.uvw + E_;       // row 1

    const float brz_c = a.conbih[j] + a.conbhh[j] + a.Wfb[j];
    const float bz_c  = a.conbih[E_+j] + a.conbhh[E_+j] + a.Wfb[E_+j];
    const float bni_c = a.conbih[2*E_+j] + a.Wfb[2*E_+j];
    const float bnh_c = a.conbhh[2*E_+j];
    const float gur0 = a.genwih[j*2],        gur1 = a.genwih[j*2+1];
    const float guz0 = a.genwih[(E_+j)*2],   guz1 = a.genwih[(E_+j)*2+1];
    const float gun0 = a.genwih[(2*E_+j)*2], gun1 = a.genwih[(2*E_+j)*2+1];
    const float brz_g = a.genbih[j] + a.genbhh[j];
    const float bz_g  = a.genbih[E_+j] + a.genbhh[E_+j];
    const float bni_g = a.genbih[2*E_+j];
    const float bnh_g = a.genbhh[2*E_+j];
    const float umb0 = a.umb[0], umb1 = a.umb[1];
    const float uvb0 = a.uvb[0], uvb1 = a.uvb[1];

    int* myslot = a.arr_main + blockIdx.x*16;
    int alive = 1;
    for (int t = 0; t < T_; ++t) {
      const ull_t* ppb = a.PP + (size_t)(t&1)*GEB + b;      // stride B_ per k
      ull_t* ppn = a.PP + (size_t)((t+1)&1)*GEB;
      const ull_t pv = ldc_u64(ppb + (size_t)j*B_);
      const float gprev = __uint_as_float((unsigned)pv);
      const float cprev = __uint_as_float((unsigned)(pv >> 32));
      float ar=0,az=0,an=0,ah=0,gr=0,gz=0,gh=0;
      for (int k4 = 0; k4 < 64; ++k4) {
        const ull_t v0 = ldc_u64(ppb + (4*k4+0)*B_);
        const ull_t v1 = ldc_u64(ppb + (4*k4+1)*B_);
        const ull_t v2 = ldc_u64(ppb + (4*k4+2)*B_);
        const ull_t v3 = ldc_u64(ppb + (4*k4+3)*B_);
        const float g0 = __uint_as_float((unsigned)v0), c0 = __uint_as_float((unsigned)(v0>>32));
        const float g1 = __uint_as_float((unsigned)v1), c1 = __uint_as_float((unsigned)(v1>>32));
        const float g2 = __uint_as_float((unsigned)v2), c2 = __uint_as_float((unsigned)(v2>>32));
        const float g3 = __uint_as_float((unsigned)v3), c3 = __uint_as_float((unsigned)(v3>>32));
        float4 v;
        v = Mr[k4];  ar += v.x*g0 + v.y*g1 + v.z*g2 + v.w*g3;
        v = Mz[k4];  az += v.x*g0 + v.y*g1 + v.z*g2 + v.w*g3;
        v = Mn[k4];  an += v.x*g0 + v.y*g1 + v.z*g2 + v.w*g3;
        v = Gwr[k4]; gr += v.x*g0 + v.y*g1 + v.z*g2 + v.w*g3;
        v = Gwz[k4]; gz += v.x*g0 + v.y*g1 + v.z*g2 + v.w*g3;
        v = Gwn[k4]; gh += v.x*g0 + v.y*g1 + v.z*g2 + v.w*g3;
        v = Whr[k4]; ar += v.x*c0 + v.y*c1 + v.z*c2 + v.w*c3;
        v = Whz[k4]; az += v.x*c0 + v.y*c1 + v.z*c2 + v.w*c3;
        v = Whn[k4]; ah += v.x*c0 + v.y*c1 + v.z*c2 + v.w*c3;
      }
      // producers of ge[t], then add its 3 contributions (u32 = 2 packed b's)
      flag_wait(a.flags + (t & 127)*16, 48*((t >> 7) + 1), s_go, alive);
      {
        const uint_t* geb = a.ge + ((size_t)(t & 127)*(768*B_) >> 1) + (b >> 1);
        const uint_t u0 = ldc_u32(geb + j*(B_/2));
        const uint_t u1 = ldc_u32(geb + (E_+j)*(B_/2));
        const uint_t u2 = ldc_u32(geb + (2*E_+j)*(B_/2));
        const int hi = b & 1;
        ar += bfu_((ushort_t)(hi ? (u0 >> 16) : u0));
        az += bfu_((ushort_t)(hi ? (u1 >> 16) : u1));
        an += bfu_((ushort_t)(hi ? (u2 >> 16) : u2));
      }
      const float r = sigm_(ar + brz_c);
      const float z = sigm_(az + bz_c);
      const float n = tanhf(an + bni_c + r*(ah + bnh_c));
      const float cn = fminf((1.0f - z)*n + z*cprev, CLIPV);
      stc_f32((float*)(ppn + (size_t)j*B_ + b) + 1, cn);    // .y = c
      slot_wait(a.arr_main, 160, myslot, 2*t+1, 2*t+1, s_go, alive);

      // ---- u partials over this wave's k-quarter of fresh c ----
      {
        const float* cq = (const float*)(ppn + b);          // +1 for .y
        float p0=0,p1=0,p2=0,p3=0;
        for (int kk = 0; kk < 64; ++kk) {
          const int k = w*64 + kk;
          const float cv = ldc_f32(cq + (size_t)k*B_*2 + 1);
          p0 += uw0[k]*cv; p1 += uw1[k]*cv; p2 += uw2[k]*cv; p3 += uw3[k]*cv;
        }
        s_up[0*256 + threadIdx.x] = p0;
        s_up[1*256 + threadIdx.x] = p1;
        s_up[2*256 + threadIdx.x] = p2;
        s_up[3*256 + threadIdx.x] = p3;
      }
      __syncthreads();
      const float m0 = s_up[lane] + s_up[64+lane] + s_up[128+lane] + s_up[192+lane] + umb0;
      const float m1 = s_up[256+lane] + s_up[320+lane] + s_up[384+lane] + s_up[448+lane] + umb1;
      const float lv0 = fmaxf(s_up[512+lane] + s_up[576+lane] + s_up[640+lane] + s_up[704+lane] + uvb0, LVMIN_);
      const float lv1 = fmaxf(s_up[768+lane] + s_up[832+lane] + s_up[896+lane] + s_up[960+lane] + uvb1, LVMIN_);
      __syncthreads();
      const float eps0 = a.epsT[(size_t)t*256 + b];
      const float eps1 = a.epsT[(size_t)t*256 + 128 + b];
      const float u0 = eps0*expf(0.5f*lv0) + m0;
      const float u1 = eps1*expf(0.5f*lv1) + m1;

      const float rg = sigm_(gr + gur0*u0 + gur1*u1 + brz_g);
      const float zg = sigm_(gz + guz0*u0 + guz1*u1 + bz_g);
      const float ng = tanhf(gun0*u0 + gun1*u1 + bni_g + rg*(gh + bnh_g));
      const float gn = fminf((1.0f - zg)*ng + zg*gprev, CLIPV);
      stc_f32((float*)(ppn + (size_t)j*B_ + b), gn);        // .x = g
      slot_wait(a.arr_main, 160, myslot, 2*t+2, 2*t+2, s_go, alive);
    }
  } else if (blockIdx.x < 224) {
    // ======================= producer =======================
    volatile int* s_go = (volatile int*)s_raw;
    const int pid = blockIdx.x - 128;
    const int tile = pid % 48, phase = pid / 48;
    const int r0 = tile*16;
    const int rl0 = w*4;                 // 4 rows per wave, all 128 b (paired)
    const float* rp0 = a.conwih + (size_t)(r0 + rl0 + 0)*576;
    const float* rp1 = a.conwih + (size_t)(r0 + rl0 + 1)*576;
    const float* rp2 = a.conwih + (size_t)(r0 + rl0 + 2)*576;
    const float* rp3 = a.conwih + (size_t)(r0 + rl0 + 3)*576;
    int alive = 1;
    for (int t = phase; t < T_; t += 2) {
      if (t >= 128)   // don't clobber ring slot until consumers are past t-128
        slot_wait(a.arr_main, 160, nullptr, 0, 2*(t-126)+1, s_go, alive);
      float a0l=0,a0h=0,a1l=0,a1h=0,a2l=0,a2h=0,a3l=0,a3h=0;
      const uint_t* efp = (const uint_t*)a.efS + (((size_t)t*GEB) >> 1) + lane;
      const uint_t* ebp = (const uint_t*)a.ebS + (((size_t)t*GEB) >> 1) + lane;
      for (int k4 = 0; k4 < 64; ++k4) {
        const float4 w0 = *(const float4*)(rp0 + 4*k4);
        const float4 w1 = *(const float4*)(rp1 + 4*k4);
        const float4 w2 = *(const float4*)(rp2 + 4*k4);
        const float4 w3 = *(const float4*)(rp3 + 4*k4);
        #pragma unroll
        for (int i = 0; i < 4; ++i) {
          const uint_t u = efp[(4*k4+i)*(B_/2)];
          const float el = bfu_((ushort_t)u), eh = bfu_((ushort_t)(u >> 16));
          const float wv0 = (&w0.x)[i], wv1 = (&w1.x)[i], wv2 = (&w2.x)[i], wv3 = (&w3.x)[i];
          a0l += wv0*el; a0h += wv0*eh; a1l += wv1*el; a1h += wv1*eh;
          a2l += wv2*el; a2h += wv2*eh; a3l += wv3*el; a3h += wv3*eh;
        }
      }
      for (int k4 = 0; k4 < 64; ++k4) {
        const float4 w0 = *(const float4*)(rp0 + 256 + 4*k4);
        const float4 w1 = *(const float4*)(rp1 + 256 + 4*k4);
        const float4 w2 = *(const float4*)(rp2 + 256 + 4*k4);
        const float4 w3 = *(const float4*)(rp3 + 256 + 4*k4);
        #pragma unroll
        for (int i = 0; i < 4; ++i) {
          const uint_t u = ebp[(4*k4+i)*(B_/2)];
          const float el = bfu_((ushort_t)u), eh = bfu_((ushort_t)(u >> 16));
          const float wv0 = (&w0.x)[i], wv1 = (&w1.x)[i], wv2 = (&w2.x)[i], wv3 = (&w3.x)[i];
          a0l += wv0*el; a0h += wv0*eh; a1l += wv1*el; a1h += wv1*eh;
          a2l += wv2*el; a2h += wv2*eh; a3l += wv3*el; a3h += wv3*eh;
        }
      }
      uint_t* gesl = a.ge + (((size_t)(t & 127)*(768*B_)) >> 1) + (size_t)(r0 + rl0)*(B_/2) + lane;
      stc_u32(gesl + 0*(B_/2), ((uint_t)bfbits_(a0h) << 16) | bfbits_(a0l));
      stc_u32(gesl + 1*(B_/2), ((uint_t)bfbits_(a1h) << 16) | bfbits_(a1l));
      stc_u32(gesl + 2*(B_/2), ((uint_t)bfbits_(a2h) << 16) | bfbits_(a2l));
      stc_u32(gesl + 3*(B_/2), ((uint_t)bfbits_(a3h) << 16) | bfbits_(a3l));
      vm_drain();
      __syncthreads();
      if (threadIdx.x == 0)
        __hip_atomic_fetch_add(a.flags + (t & 127)*16, 1, __ATOMIC_RELAXED, __HIP_MEMORY_SCOPE_AGENT);
    }
  } else {
    // ======================= output MLP =======================
    __hip_bfloat16* s_fw  = (__hip_bfloat16*)s_raw;              // [256][64] 32768 B
    __hip_bfloat16* s_f1T = (__hip_bfloat16*)(s_raw + 32768);    // [64][80] 10240 B
    __hip_bfloat16* s_clT = (__hip_bfloat16*)(s_raw + 43008);    // [80][64] 10240 B
    float* s_g  = (float*)(s_raw + 53248);                       // [4][256] 4096 B
    float* s_f  = (float*)(s_raw + 57344);                       // [4][64]  1024 B
    float* s_h1 = (float*)(s_raw + 58368);                       // [4][80]  1280 B
    volatile int* s_go = (volatile int*)(s_raw + 59648);
    for (int idx = threadIdx.x; idx < 16384; idx += 256) {
      const int k = idx >> 6, fd = idx & 63;
      s_fw[idx] = __float2bfloat16(a.facw[(size_t)fd*E_ + k]);
    }
    for (int idx = threadIdx.x; idx < 5120; idx += 256) {
      const int kf = idx / H1_, hd = idx % H1_;
      s_f1T[idx] = __float2bfloat16(a.f1w[(size_t)hd*64 + kf]);
    }
    for (int idx = threadIdx.x; idx < 5120; idx += 256) {
      const int kh = idx >> 6, od = idx & 63;
      s_clT[idx] = __float2bfloat16(a.clw[(size_t)od*H1_ + kh]);
    }
    __syncthreads();
    const int oid = blockIdx.x - 224;
    int bw = oid*4 + w;
    bw = __builtin_amdgcn_readfirstlane(bw);
    const float facb_l = a.facb[lane];
    const float f1b_a  = a.f1b[lane];
    const float f1b_b  = (lane < 16) ? a.f1b[64 + lane] : 0.0f;
    const float clb_l  = a.clb[lane];
    int* myslot = a.arr_main + (128 + oid)*16;
    int alive = 1;
    for (int t = 0; t <= T_; ++t) {
      const int tt = t - 1;
      if (tt >= 0) {
        const float* ppx = (const float*)(a.PP + (size_t)((tt+1)&1)*GEB);
        #pragma unroll
        for (int i = 0; i < 4; ++i) {
          const int k = lane + 64*i;
          s_g[w*256 + k] = ldc_f32(ppx + ((size_t)k*B_ + bw)*2);
        }
        __syncthreads();
        float f = facb_l;
        for (int k = 0; k < 256; ++k)
          f += __bfloat162float(s_fw[k*64 + lane]) * s_g[w*256 + k];
        s_f[w*64 + lane] = f;
        __syncthreads();
        float h1a = f1b_a, h1b = f1b_b;
        for (int kf = 0; kf < 64; ++kf) {
          const float fv = s_f[w*64 + kf];
          h1a += __bfloat162float(s_f1T[kf*H1_ + lane]) * fv;
          if (lane < 16) h1b += __bfloat162float(s_f1T[kf*H1_ + 64 + lane]) * fv;
        }
        s_h1[w*H1_ + lane] = fmaxf(h1a, 0.0f);
        if (lane < 16) s_h1[w*H1_ + 64 + lane] = fmaxf(h1b, 0.0f);
        __syncthreads();
        float o = clb_l;
        for (int kh = 0; kh < H1_; ++kh)
          o += __bfloat162float(s_clT[kh*64 + lane]) * s_h1[w*H1_ + kh];
        a.out[((size_t)bw*T_ + tt)*DOUT_ + lane] = o;
      }
      if (t == T_) break;
      slot_wait(a.arr_main, 160, myslot, 2*t+1, 2*t+1, s_go, alive);
      slot_wait(a.arr_main, 160, myslot, 2*t+2, 2*t+2, s_go, alive);
    }
  }
}

// ------------------------- host launcher ------------------------------------

extern "C" void kernel_launch(void* const* d_in, const int* in_sizes, int n_in,
                              void* d_out, int out_size, void* d_ws, size_t ws_size,
                              hipStream_t stream) {
  const float* x      = (const float*)d_in[0];
  const float* eps_g0 = (const float*)d_in[1];
  const float* eps_u  = (const float*)d_in[2];
  const float* egf_wih = (const float*)d_in[3],  *egf_whh = (const float*)d_in[4];
  const float* egf_bih = (const float*)d_in[5],  *egf_bhh = (const float*)d_in[6];
  const float* egb_wih = (const float*)d_in[7],  *egb_whh = (const float*)d_in[8];
  const float* egb_bih = (const float*)d_in[9],  *egb_bhh = (const float*)d_in[10];
  const float* ecf_wih = (const float*)d_in[11], *ecf_whh = (const float*)d_in[12];
  const float* ecf_bih = (const float*)d_in[13], *ecf_bhh = (const float*)d_in[14];
  const float* ecb_wih = (const float*)d_in[15], *ecb_whh = (const float*)d_in[16];
  const float* ecb_bih = (const float*)d_in[17], *ecb_bhh = (const float*)d_in[18];
  const float* con_wih = (const float*)d_in[19], *con_whh = (const float*)d_in[20];
  const float* con_bih = (const float*)d_in[21], *con_bhh = (const float*)d_in[22];
  const float* gen_wih = (const float*)d_in[23], *gen_whh = (const float*)d_in[24];
  const float* gen_bih = (const float*)d_in[25], *gen_bhh = (const float*)d_in[26];
  const float* g0m_w = (const float*)d_in[27], *g0m_b = (const float*)d_in[28];
  const float* g0v_w = (const float*)d_in[29], *g0v_b = (const float*)d_in[30];
  const float* um_w = (const float*)d_in[31], *um_b = (const float*)d_in[32];
  const float* uv_w = (const float*)d_in[33], *uv_b = (const float*)d_in[34];
  const float* fac_w = (const float*)d_in[35], *fac_b = (const float*)d_in[36];
  const float* f1_w = (const float*)d_in[37], *f1_b = (const float*)d_in[38];
  const float* cl_w = (const float*)d_in[39], *cl_b = (const float*)d_in[40];
  float* out = (float*)d_out;
  (void)ws_size; (void)in_sizes; (void)n_in; (void)out_size;

  // Workspace layout — total 167,262,208 B <= proven 167,297,024 B.
  char* ws = (char*)d_ws;
  const size_t o_xT   = 0;             // f32 [T][DIN][B]        32,768,000
  const size_t o_ge   = 0;             // bf16 [128][768][B]     25,165,824 (alias, xT dead)
  const size_t o_efS  = 32768000ul;    // bf16 [T][E][B]         65,536,000
  const size_t o_ebS  = 98304000ul;    //                        65,536,000
  const size_t o_epsT = 163840000ul;   // f32 [T][2][B]           1,024,000
  const size_t o_M    = 164864000ul;   // f32 [768][E]              786,432
  const size_t o_Wfb  = 165650432ul;   // f32 [768]                   4,096
  const size_t o_hT   = 165654528ul;   // f32 [4][2][E][B]        1,048,576
  const size_t o_PP   = 166703104ul;   // f32x2 [2][E][B]           524,288
  const size_t o_ctl  = 167227392ul;   // int slots                  34,816
  const size_t o_end  = 167262208ul;

  float* xT = (float*)(ws + o_xT);
  uint_t* ge = (uint_t*)(ws + o_ge);
  __hip_bfloat16* efS = (__hip_bfloat16*)(ws + o_efS);
  __hip_bfloat16* ebS = (__hip_bfloat16*)(ws + o_ebS);
  float* epsT = (float*)(ws + o_epsT);
  float* M = (float*)(ws + o_M);
  float* Wfb = (float*)(ws + o_Wfb);
  float* hT = (float*)(ws + o_hT);
  ull_t* PP = (ull_t*)(ws + o_PP);
  int* ctl = (int*)(ws + o_ctl);
  int* arr_main = ctl;           // 160 slots * 16 ints
  int* flags    = ctl + 2560;    // 128 slots * 16 ints
  int* arr_enc  = ctl + 4608;    // 4*64 slots * 16 ints

  // zero the ENTIRE state+control region (hT, PP, all slots/flags)
  hipMemsetAsync(ws + o_hT, 0, o_end - o_hT, stream);

  k_transpose_x<<<dim3(T_, 2), 256, 0, stream>>>(x, xT);
  k_transpose_eps<<<T_, 256, 0, stream>>>(eps_u, epsT);
  k_composite<<<768, 256, 0, stream>>>(con_wih, fac_w, fac_b, M, Wfb);

  EncArgs ea;
  ea.xT = xT;
  ea.wih[0] = egf_wih; ea.whh[0] = egf_whh; ea.bih[0] = egf_bih; ea.bhh[0] = egf_bhh;
  ea.wih[1] = ecf_wih; ea.whh[1] = ecf_whh; ea.bih[1] = ecf_bih; ea.bhh[1] = ecf_bhh;
  ea.wih[2] = egb_wih; ea.whh[2] = egb_whh; ea.bih[2] = egb_bih; ea.bhh[2] = egb_bhh;
  ea.wih[3] = ecb_wih; ea.whh[3] = ecb_whh; ea.bih[3] = ecb_bih; ea.bhh[3] = ecb_bhh;
  ea.hT = hT; ea.efS = efS; ea.ebS = ebS; ea.arr = arr_enc;
  k_encoder<<<256, 256, 0, stream>>>(ea);

  k_g0<<<128, 256, 0, stream>>>(hT, g0m_w, g0m_b, g0v_w, g0v_b, eps_g0, (float*)PP);

  GenAll ga;
  ga.M = M; ga.conwhh = con_whh; ga.genwhh = gen_whh;
  ga.conbih = con_bih; ga.conbhh = con_bhh; ga.Wfb = Wfb;
  ga.genwih = gen_wih; ga.genbih = gen_bih; ga.genbhh = gen_bhh;
  ga.umw = um_w; ga.umb = um_b; ga.uvw = uv_w; ga.uvb = uv_b;
  ga.epsT = epsT; ga.conwih = con_wih;
  ga.efS = efS; ga.ebS = ebS; ga.ge = ge; ga.PP = PP;
  ga.facw = fac_w; ga.facb = fac_b;
  ga.f1w = f1_w; ga.f1b = f1_b; ga.clw = cl_w; ga.clb = cl_b;
  ga.out = out;
  ga.arr_main = arr_main; ga.flags = flags;
  k_generator<<<256, 256, 0, stream>>>(ga);
}